// Round 5
// baseline (199.940 us; speedup 1.0000x reference)
//
#include <hip/hip_runtime.h>
#include <hip/hip_bf16.h>

#define DEV static __device__ __forceinline__

constexpr int B=16, N=128, FIN=128, FOUT=256, EOUT=64, BINW=14, BOUT=64, CI=64, L1=256;

// ---- scratch layout in d_ws (float offsets) ----
constexpr int O_H   = 0;                       // [B,N,FOUT]
constexpr int O_S   = O_H  + B*N*FOUT;         // [B,N]
constexpr int O_SU  = O_S  + B*N;
constexpr int O_SV  = O_SU + B*N;
constexpr int O_ATT = O_SV + B*N;              // [B,N,N]
constexpr int O_ZF  = O_ATT+ B*N*N;            // [B,N,CI]
constexpr int O_ZB  = O_ZF + B*N*CI;
constexpr int O_RF  = O_ZB + B*N*CI;
constexpr int O_RB  = O_RF + B*N*CI;
constexpr int O_H1  = O_RB + B*N*CI;           // [B,N,L1] : partial = h1@fco_w[2CI:,:] + fco_b

DEV float bf16_to_f32(unsigned short u){
  unsigned int x = ((unsigned int)u) << 16; float f;
  __builtin_memcpy(&f, &x, 4); return f;
}
DEV void bf2x(unsigned int u, float& lo, float& hi){
  unsigned int a = u << 16, b = u & 0xFFFF0000u;
  __builtin_memcpy(&lo, &a, 4); __builtin_memcpy(&hi, &b, 4);
}
DEV float lrelu(float x){ return x > 0.f ? x : 0.01f * x; }
DEV float bcastf(float v, int lane){
  return __builtin_bit_cast(float, __builtin_amdgcn_readlane(__builtin_bit_cast(int, v), lane));
}
DEV float ldf(const void* p, int i, int m){
  return m ? bf16_to_f32(((const unsigned short*)p)[i]) : ((const float*)p)[i];
}
// block-parallel dtype detect (bf16 ~100% of sampled exps in [100,140]; f32 ~58%)
DEV int blk_mode(const void* x, int nt, int tid){
  const unsigned short* u = (const unsigned short*)x;
  int e = (u[tid & 255] >> 7) & 0xFF;
  int cnt = __syncthreads_count(e >= 100 && e <= 140);
  return cnt * 4 >= nt * 3;
}

// K1: h = x@W ; s = h·fcc_w ; P,Q (LDS only) ; su/sv fused (sv[r]==sv[r+64])
// 512 blocks x 4 rows: 2 blocks/CU.
__global__ __launch_bounds__(256, 2) void k_h_pq(const void* __restrict__ xr,
                                                 const void* __restrict__ Wp,
                                                 const void* __restrict__ Ap,
                                                 const void* __restrict__ fccwp,
                                                 const void* __restrict__ fcwp,
                                                 float* __restrict__ ws){
  int blk = blockIdx.x, tid = threadIdx.x;
  int b = blk >> 5, i0 = (blk & 31) * 4;
  __shared__ __align__(16) float xl[4*FIN];
  __shared__ __align__(16) float hrow[4*FOUT];
  __shared__ __align__(16) float pl[4*EOUT];
  __shared__ __align__(16) float ql[4*EOUT];
  __shared__ float red[16];
  int mode = blk_mode(xr, 256, tid);
  if (mode){
    const unsigned short* xu = (const unsigned short*)xr + (size_t)(b*N + i0)*FIN;
    for (int t = tid; t < 4*FIN/8; t += 256){
      uint4 u4 = ((const uint4*)xu)[t];
      float* o = &xl[t*8];
      bf2x(u4.x,o[0],o[1]); bf2x(u4.y,o[2],o[3]); bf2x(u4.z,o[4],o[5]); bf2x(u4.w,o[6],o[7]);
    }
  } else {
    const float* xf = (const float*)xr + (size_t)(b*N + i0)*FIN;
    for (int t4 = tid; t4 < 4*FIN/4; t4 += 256)
      *(float4*)&xl[t4*4] = ((const float4*)xf)[t4];
  }
  __syncthreads();
  int f = tid;
  float acc[4] = {0,0,0,0};
  if (mode){
    const unsigned short* Wu = (const unsigned short*)Wp;
    #pragma unroll 2
    for (int c = 0; c < FIN; c += 4){
      float w0 = bf16_to_f32(Wu[(c+0)*FOUT + f]);
      float w1 = bf16_to_f32(Wu[(c+1)*FOUT + f]);
      float w2 = bf16_to_f32(Wu[(c+2)*FOUT + f]);
      float w3 = bf16_to_f32(Wu[(c+3)*FOUT + f]);
      #pragma unroll
      for (int r = 0; r < 4; ++r){
        float4 x4 = *(const float4*)&xl[r*FIN + c];
        acc[r] += x4.x*w0 + x4.y*w1 + x4.z*w2 + x4.w*w3;
      }
    }
  } else {
    const float* Wf = (const float*)Wp;
    #pragma unroll 2
    for (int c = 0; c < FIN; c += 4){
      float w0 = Wf[(c+0)*FOUT + f];
      float w1 = Wf[(c+1)*FOUT + f];
      float w2 = Wf[(c+2)*FOUT + f];
      float w3 = Wf[(c+3)*FOUT + f];
      #pragma unroll
      for (int r = 0; r < 4; ++r){
        float4 x4 = *(const float4*)&xl[r*FIN + c];
        acc[r] += x4.x*w0 + x4.y*w1 + x4.z*w2 + x4.w*w3;
      }
    }
  }
  float fw = ldf(fccwp, f, mode);
  #pragma unroll
  for (int r = 0; r < 4; ++r){
    ws[O_H + (b*N + i0 + r)*FOUT + f] = acc[r];
    hrow[r*FOUT + f] = acc[r];
  }
  #pragma unroll
  for (int r = 0; r < 4; ++r){
    float v = acc[r] * fw;
    for (int off = 32; off; off >>= 1) v += __shfl_down(v, off);
    if ((tid & 63) == 0) red[(tid >> 6)*4 + r] = v;
  }
  __syncthreads();
  if (tid < 4){
    float s = red[tid] + red[4+tid] + red[8+tid] + red[12+tid];
    ws[O_S + b*N + i0 + tid] = s;
  }
  // P/Q into LDS (4 waves: which = P/Q, hh = row-half); hrow reads wave-uniform
  {
    int o = tid & 63, which = (tid >> 6) & 1, hh = tid >> 7;
    float a2[2] = {0.f,0.f};
    if (mode){
      const unsigned short* Au = (const unsigned short*)Ap;
      #pragma unroll 2
      for (int c = 0; c < FOUT; c += 4){
        float w0 = bf16_to_f32(Au[(which*FOUT + c+0)*EOUT + o]);
        float w1 = bf16_to_f32(Au[(which*FOUT + c+1)*EOUT + o]);
        float w2 = bf16_to_f32(Au[(which*FOUT + c+2)*EOUT + o]);
        float w3 = bf16_to_f32(Au[(which*FOUT + c+3)*EOUT + o]);
        #pragma unroll
        for (int r = 0; r < 2; ++r){
          float4 h4 = *(const float4*)&hrow[(hh*2+r)*FOUT + c];
          a2[r] += h4.x*w0 + h4.y*w1 + h4.z*w2 + h4.w*w3;
        }
      }
    } else {
      const float* Af = (const float*)Ap;
      #pragma unroll 2
      for (int c = 0; c < FOUT; c += 4){
        float w0 = Af[(which*FOUT + c+0)*EOUT + o];
        float w1 = Af[(which*FOUT + c+1)*EOUT + o];
        float w2 = Af[(which*FOUT + c+2)*EOUT + o];
        float w3 = Af[(which*FOUT + c+3)*EOUT + o];
        #pragma unroll
        for (int r = 0; r < 2; ++r){
          float4 h4 = *(const float4*)&hrow[(hh*2+r)*FOUT + c];
          a2[r] += h4.x*w0 + h4.y*w1 + h4.z*w2 + h4.w*w3;
        }
      }
    }
    float* dst = which ? ql : pl;
    #pragma unroll
    for (int r = 0; r < 2; ++r) dst[(hh*2+r)*EOUT + o] = a2[r];
  }
  __syncthreads();
  // su for rows i0..i0+3 ; sv for pairs (value keyed by j2=(2r)&127; sv[r]==sv[r+64])
  {
    int o = tid & 63, w = tid >> 6;
    float fw2 = ldf(fcwp, o, mode);
    int w2 = (w < 2) ? w : 0;            // waves 2,3 compute a dummy s3 (not stored)
    float s1 = lrelu(pl[w*EOUT + o]        + ql[w*EOUT + o])        * fw2;
    float s3 = lrelu(pl[(2*w2)*EOUT + o]   + ql[(2*w2+1)*EOUT + o]) * fw2;
    for (int off = 32; off; off >>= 1){
      s1 += __shfl_down(s1, off); s3 += __shfl_down(s3, off);
    }
    if (o == 0){
      ws[O_SU + b*N + i0 + w] = s1;
      if (w < 2){
        int r1 = (i0 >> 1) + w;
        ws[O_SV + b*N + r1]      = s3;
        ws[O_SV + b*N + r1 + 64] = s3;
      }
    }
  }
}

struct AttArgs { const void *we,*x,*wfcw,*wfcb,*fcw,*fcb,*fccb,*wihf,*bihf,*bhhf,*wihb,*bihb,*bhhb; };

// K2: per block: TWO pairs of (b,i) rows (4 rows total), looped.
// edge-MLP + mask + softmax -> att ; hn_pre ; z.  512 blocks = 2/CU.
__global__ __launch_bounds__(256) void k_att(AttArgs A, const int* __restrict__ adj,
                                             float* __restrict__ ws){
  int blk = blockIdx.x, tid = threadIdx.x;
  int half = tid >> 7, j = tid & 127, wv = (tid >> 6) & 1;
  __shared__ __align__(16) float wel[2][N*BINW];
  __shared__ __align__(16) float hnp[2][N];
  __shared__ __align__(16) float wfcwl[BINW*BOUT];
  __shared__ __align__(16) float wfcbl[BOUT];
  __shared__ __align__(16) float fcw2l[BOUT];
  __shared__ float red2[2][2];
  int mode = blk_mode(A.x, 256, tid);
  for (int t = tid; t < BINW*BOUT; t += 256) wfcwl[t] = ldf(A.wfcw, t, mode);
  if (tid < BOUT){ wfcbl[tid] = ldf(A.wfcb, tid, mode); fcw2l[tid] = ldf(A.fcw, EOUT + tid, mode); }
  float fcbv = ldf(A.fcb, 0, mode), fccbv = ldf(A.fccb, 0, mode);
  const float* R = ws;
  for (int pr = 0; pr < 2; ++pr){
    int tau = blk*4 + pr*2 + half;
    int b = tau >> 7, i = tau & 127;
    if (pr) __syncthreads();   // protect wel/hnp/red2 reuse across iterations
    if (mode){
      const unsigned short* weu = (const unsigned short*)A.we + (size_t)(b*N + i)*N*BINW;
      for (int t = j; t < N*BINW/8; t += 128){
        uint4 q = ((const uint4*)weu)[t];
        float* o = &wel[half][t*8];
        bf2x(q.x,o[0],o[1]); bf2x(q.y,o[2],o[3]); bf2x(q.z,o[4],o[5]); bf2x(q.w,o[6],o[7]);
      }
    } else {
      const float* wef = (const float*)A.we + (size_t)(b*N + i)*N*BINW;
      for (int t4 = j; t4 < N*BINW/4; t4 += 128)
        *(float4*)&wel[half][t4*4] = ((const float4*)wef)[t4];
    }
    __syncthreads();
    float wr[BINW];
    #pragma unroll
    for (int t = 0; t < BINW; ++t) wr[t] = wel[half][j*BINW + t];
    float wcon = 0.f;
    for (int o = 0; o < BOUT; o += 4){
      float4 bb = *(const float4*)&wfcbl[o];
      float w0 = bb.x, w1 = bb.y, w2 = bb.z, w3 = bb.w;
      #pragma unroll
      for (int t = 0; t < BINW; ++t){
        float4 w4 = *(const float4*)&wfcwl[t*BOUT + o];
        w0 = fmaf(wr[t], w4.x, w0); w1 = fmaf(wr[t], w4.y, w1);
        w2 = fmaf(wr[t], w4.z, w2); w3 = fmaf(wr[t], w4.w, w3);
      }
      float4 f4 = *(const float4*)&fcw2l[o];
      wcon += lrelu(w0)*f4.x + lrelu(w1)*f4.y + lrelu(w2)*f4.z + lrelu(w3)*f4.w;
    }
    float econ = (i < 64) ? R[O_SU + b*N + 2*i + (j >= 64 ? 1 : 0)]
                          : R[O_SV + b*N + j];
    float etot = econ + wcon + fcbv;
    float m = (adj[(b*N + i)*N + j] > 0) ? etot : -9e15f;
    float mx = m;
    for (int off = 32; off; off >>= 1) mx = fmaxf(mx, __shfl_xor(mx, off));
    if ((tid & 63) == 0) red2[half][wv] = mx;
    __syncthreads();
    mx = fmaxf(red2[half][0], red2[half][1]);
    float ev = expf(m - mx);
    float sum = ev;
    for (int off = 32; off; off >>= 1) sum += __shfl_xor(sum, off);
    __syncthreads();
    if ((tid & 63) == 0) red2[half][wv] = sum;
    __syncthreads();
    sum = red2[half][0] + red2[half][1];
    float att = ev / sum;
    ws[O_ATT + (b*N + i)*N + j] = att;
    float sbi = R[O_S + b*N + i];
    hnp[half][j] = lrelu(att * sbi + fccbv);
    __syncthreads();
    // z[b,i,c] both directions (per half: 2 waves = 2 directions)
    {
      int d = wv, c = tid & 63;
      float acc = ldf(d ? A.bihb : A.bihf, c, mode) + ldf(d ? A.bhhb : A.bhhf, c, mode);
      const void* wihp = d ? A.wihb : A.wihf;
      if (mode){
        const uint4* wq = (const uint4*)((const unsigned short*)wihp + c*N);
        #pragma unroll 4
        for (int k = 0; k < N; k += 8){
          uint4 q = wq[k >> 3];
          float w0,w1,w2,w3,w4,w5,w6,w7;
          bf2x(q.x,w0,w1); bf2x(q.y,w2,w3); bf2x(q.z,w4,w5); bf2x(q.w,w6,w7);
          float4 h0 = *(const float4*)&hnp[half][k];
          float4 h1 = *(const float4*)&hnp[half][k+4];
          acc += h0.x*w0 + h0.y*w1 + h0.z*w2 + h0.w*w3
               + h1.x*w4 + h1.y*w5 + h1.z*w6 + h1.w*w7;
        }
      } else {
        const float* wf = (const float*)wihp + c*N;
        #pragma unroll 8
        for (int k = 0; k < N; k += 4){
          float4 h4 = *(const float4*)&hnp[half][k];
          float4 w4 = *(const float4*)&wf[k];
          acc += h4.x*w4.x + h4.y*w4.y + h4.z*w4.z + h4.w*w4.w;
        }
      }
      ws[(d ? O_ZB : O_ZF) + (b*N + i)*CI + c] = acc;
    }
  }
}

// K3: blocks 0..31: serial RNN chains (wave 0).
//     blocks 32..543: h1 = att@h (4 rows) FUSED with partial = h1@fco_w[2CI:,:]+fco_b.
// The partial GEMM (2/3 of old K4's work) hides under the RNN chains' latency.
__global__ __launch_bounds__(256, 1) void k_rnn_h1(const void* __restrict__ xr,
                                                   const void* __restrict__ whhf,
                                                   const void* __restrict__ whhb,
                                                   const void* __restrict__ fcowp,
                                                   const void* __restrict__ fcobp,
                                                   float* __restrict__ ws){
  __shared__ __align__(16) float sh[N*CI];   // rnn: 32 KB; h1: attT (512) + h1 rows (1024)
  int blk = blockIdx.x, tid = threadIdx.x;
  int mode = blk_mode(xr, 256, tid);
  const float* R = ws;
  if (blk < 32){
    int d = blk >> 4, b = blk & 15;
    const int zb = (d ? O_ZB : O_ZF) + b*N*CI;
    const int ob = (d ? O_RB : O_RF) + b*N*CI;
    for (int it = tid; it < N*CI/4; it += 256)
      *(float4*)&sh[it*4] = *(const float4*)&ws[zb + it*4];
    __syncthreads();
    if (tid < 64){
      int c = tid;
      const void* whhp = d ? whhb : whhf;
      float wreg[CI];
      if (mode){
        const uint4* wq = (const uint4*)((const unsigned short*)whhp + c*CI);
        #pragma unroll
        for (int k = 0; k < CI; k += 8){
          uint4 q = wq[k >> 3];
          bf2x(q.x,wreg[k+0],wreg[k+1]); bf2x(q.y,wreg[k+2],wreg[k+3]);
          bf2x(q.z,wreg[k+4],wreg[k+5]); bf2x(q.w,wreg[k+6],wreg[k+7]);
        }
      } else {
        const float* wf = (const float*)whhp + c*CI;
        #pragma unroll
        for (int k = 0; k < CI; k += 4){
          float4 w4 = *(const float4*)&wf[k];
          wreg[k]=w4.x; wreg[k+1]=w4.y; wreg[k+2]=w4.z; wreg[k+3]=w4.w;
        }
      }
      const int step = d ? -1 : 1;
      int tt = d ? (N-1) : 0;
      float hv = 0.f;
      float z = sh[tt*CI + c];    // single wave: DS ops in-order, no barrier needed
      for (int t = 0; t < N; ++t){
        int ti = tt + step; ti = ti < 0 ? 0 : (ti > N-1 ? N-1 : ti);
        float znext = sh[ti*CI + c];
        float s[CI];
        #pragma unroll
        for (int k = 0; k < CI; ++k) s[k] = bcastf(hv, k);   // batched readlanes
#if __has_builtin(__builtin_amdgcn_sched_barrier)
        __builtin_amdgcn_sched_barrier(0);
#endif
        float a0 = z, a1 = 0.f, a2 = 0.f, a3 = 0.f;
        #pragma unroll
        for (int k = 0; k < CI; k += 4){
          a0 = fmaf(s[k+0], wreg[k+0], a0);
          a1 = fmaf(s[k+1], wreg[k+1], a1);
          a2 = fmaf(s[k+2], wreg[k+2], a2);
          a3 = fmaf(s[k+3], wreg[k+3], a3);
        }
        float x = (a0+a1)+(a2+a3);
        x = fminf(15.f, fmaxf(-15.f, x));
        float p = __expf(2.f * x);
        hv = (p - 1.f) * __builtin_amdgcn_rcpf(p + 1.f);
        sh[tt*CI + c] = hv;
        z = znext;
        tt += step;
      }
    }
    __syncthreads();
    for (int it = tid; it < N*CI/4; it += 256)
      *(float4*)&ws[ob + it*4] = *(const float4*)&sh[it*4];
  } else {
    int task = blk - 32;                 // 0..511, 4 rows each
    int b = task >> 5, i0 = (task & 31) * 4;
    int f = tid;
    for (int t = tid; t < 4*N; t += 256){
      int r = t >> 7, k = t & 127;
      sh[k*4 + r] = R[O_ATT + (b*N + i0 + r)*N + k];
    }
    __syncthreads();
    float acc[4] = {0,0,0,0};
    #pragma unroll 4
    for (int k = 0; k < N; ++k){
      float hv = R[O_H + (b*N + k)*FOUT + f];
      float4 a0 = *(const float4*)&sh[k*4];
      acc[0] += a0.x*hv; acc[1] += a0.y*hv; acc[2] += a0.z*hv; acc[3] += a0.w*hv;
    }
    // h1 rows -> LDS, then partial = h1 @ fco_w[2CI:,:] + fco_b  (hidden under RNN)
    float* h1l = sh + 4*N;     // 1024 floats
    #pragma unroll
    for (int r = 0; r < 4; ++r) h1l[r*FOUT + f] = acc[r];
    __syncthreads();
    float bias = ldf(fcobp, f, mode);
    float p4[4] = {bias, bias, bias, bias};
    if (mode){
      const unsigned short* fu = (const unsigned short*)fcowp + (size_t)(2*CI)*L1;
      #pragma unroll 2
      for (int k = 0; k < FOUT; k += 4){
        float w0 = bf16_to_f32(fu[(k+0)*L1 + f]);
        float w1 = bf16_to_f32(fu[(k+1)*L1 + f]);
        float w2 = bf16_to_f32(fu[(k+2)*L1 + f]);
        float w3 = bf16_to_f32(fu[(k+3)*L1 + f]);
        #pragma unroll
        for (int r = 0; r < 4; ++r){
          float4 hv = *(const float4*)&h1l[r*FOUT + k];   // wave-uniform -> LDS broadcast
          p4[r] += hv.x*w0 + hv.y*w1 + hv.z*w2 + hv.w*w3;
        }
      }
    } else {
      const float* ff = (const float*)fcowp + (size_t)(2*CI)*L1;
      #pragma unroll 2
      for (int k = 0; k < FOUT; k += 4){
        float w0 = ff[(k+0)*L1 + f];
        float w1 = ff[(k+1)*L1 + f];
        float w2 = ff[(k+2)*L1 + f];
        float w3 = ff[(k+3)*L1 + f];
        #pragma unroll
        for (int r = 0; r < 4; ++r){
          float4 hv = *(const float4*)&h1l[r*FOUT + k];
          p4[r] += hv.x*w0 + hv.y*w1 + hv.z*w2 + hv.w*w3;
        }
      }
    }
    #pragma unroll
    for (int r = 0; r < 4; ++r)
      ws[O_H1 + (b*N + i0 + r)*L1 + f] = p4[r];
  }
}

// K4 (thin): out = elu(partial + cat(lrelu(rf),lrelu(rb)) @ fco_w[0:2CI,:])
// 256 blocks x 8 rows: weight loads amortize over 8 rows.
__global__ __launch_bounds__(256, 2) void k_out(const void* __restrict__ xr,
                                                const void* __restrict__ fcowp,
                                                const float* __restrict__ R, void* dout){
  int blk = blockIdx.x, tid = threadIdx.x;
  int b = blk >> 4, i0 = (blk & 15) * 8;
  __shared__ __align__(16) float inl[8*2*CI];   // 8 rows x 128
  int mode = blk_mode(xr, 256, tid);
  for (int t = tid; t < 8*2*CI; t += 256){
    int r = t >> 7, k = t & 127;
    int row = b*N + i0 + r;
    inl[r*128 + k] = (k < CI) ? lrelu(R[O_RF + row*CI + k])
                              : lrelu(R[O_RB + row*CI + (k - CI)]);
  }
  __syncthreads();
  int l = tid;
  float acc[8];
  #pragma unroll
  for (int r = 0; r < 8; ++r) acc[r] = R[O_H1 + (b*N + i0 + r)*L1 + l];  // partial (incl bias+h1 part)
  if (mode){
    const unsigned short* fu = (const unsigned short*)fcowp;
    #pragma unroll 2
    for (int k = 0; k < 2*CI; k += 4){
      float w0 = bf16_to_f32(fu[(k+0)*L1 + l]);
      float w1 = bf16_to_f32(fu[(k+1)*L1 + l]);
      float w2 = bf16_to_f32(fu[(k+2)*L1 + l]);
      float w3 = bf16_to_f32(fu[(k+3)*L1 + l]);
      #pragma unroll
      for (int r = 0; r < 8; ++r){
        float4 v = *(const float4*)&inl[r*128 + k];
        acc[r] += v.x*w0 + v.y*w1 + v.z*w2 + v.w*w3;
      }
    }
  } else {
    const float* ff = (const float*)fcowp;
    #pragma unroll 2
    for (int k = 0; k < 2*CI; k += 4){
      float w0 = ff[(k+0)*L1 + l];
      float w1 = ff[(k+1)*L1 + l];
      float w2 = ff[(k+2)*L1 + l];
      float w3 = ff[(k+3)*L1 + l];
      #pragma unroll
      for (int r = 0; r < 8; ++r){
        float4 v = *(const float4*)&inl[r*128 + k];
        acc[r] += v.x*w0 + v.y*w1 + v.z*w2 + v.w*w3;
      }
    }
  }
  #pragma unroll
  for (int r = 0; r < 8; ++r){
    float o = acc[r] > 0.f ? acc[r] : expm1f(acc[r]);
    int idx = (b*N + i0 + r)*L1 + l;
    if (mode) ((__hip_bfloat16*)dout)[idx] = __float2bfloat16(o);
    else      ((float*)dout)[idx] = o;
  }
}

extern "C" void kernel_launch(void* const* d_in, const int* in_sizes, int n_in,
                              void* d_out, int out_size, void* d_ws, size_t ws_size,
                              hipStream_t stream){
  (void)in_sizes; (void)n_in; (void)out_size; (void)ws_size;
  float* ws = (float*)d_ws;
  AttArgs A;
  A.we = d_in[2]; A.x = d_in[0]; A.wfcw = d_in[5]; A.wfcb = d_in[6];
  A.fcw = d_in[7]; A.fcb = d_in[8]; A.fccb = d_in[10];
  A.wihf = d_in[11]; A.bihf = d_in[13]; A.bhhf = d_in[14];
  A.wihb = d_in[15]; A.bihb = d_in[17]; A.bhhb = d_in[18];
  hipLaunchKernelGGL(k_h_pq,   dim3(512),    dim3(256), 0, stream,
                     d_in[0], d_in[3], d_in[4], d_in[9], d_in[7], ws);
  hipLaunchKernelGGL(k_att,    dim3(B*N/4),  dim3(256), 0, stream, A, (const int*)d_in[1], ws);
  hipLaunchKernelGGL(k_rnn_h1, dim3(544),    dim3(256), 0, stream,
                     d_in[0], d_in[12], d_in[16], d_in[19], d_in[20], ws);
  hipLaunchKernelGGL(k_out,    dim3(256),    dim3(256), 0, stream,
                     d_in[0], d_in[19], ws, d_out);
}

// Round 6
// 192.440 us; speedup vs baseline: 1.0390x; 1.0390x over previous
//
#include <hip/hip_runtime.h>
#include <hip/hip_bf16.h>

#define DEV static __device__ __forceinline__

constexpr int B=16, N=128, FIN=128, FOUT=256, EOUT=64, BINW=14, BOUT=64, CI=64, L1=256;

// ---- scratch layout in d_ws (float offsets) ----
constexpr int O_H   = 0;                       // [B,N,FOUT]
constexpr int O_S   = O_H  + B*N*FOUT;         // [B,N]
constexpr int O_SU  = O_S  + B*N;
constexpr int O_SV  = O_SU + B*N;
constexpr int O_ATT = O_SV + B*N;              // [B,N,N]
constexpr int O_ZF  = O_ATT+ B*N*N;            // [B,N,CI]
constexpr int O_ZB  = O_ZF + B*N*CI;
constexpr int O_RF  = O_ZB + B*N*CI;
constexpr int O_RB  = O_RF + B*N*CI;
constexpr int O_H1  = O_RB + B*N*CI;           // [B,N,L1] : partial = h1@fco_w[2CI:,:] + fco_b

DEV float bf16_to_f32(unsigned short u){
  unsigned int x = ((unsigned int)u) << 16; float f;
  __builtin_memcpy(&f, &x, 4); return f;
}
DEV void bf2x(unsigned int u, float& lo, float& hi){
  unsigned int a = u << 16, b = u & 0xFFFF0000u;
  __builtin_memcpy(&lo, &a, 4); __builtin_memcpy(&hi, &b, 4);
}
DEV float lrelu(float x){ return x > 0.f ? x : 0.01f * x; }
DEV float bcastf(float v, int lane){
  return __builtin_bit_cast(float, __builtin_amdgcn_readlane(__builtin_bit_cast(int, v), lane));
}
DEV float ldf(const void* p, int i, int m){
  return m ? bf16_to_f32(((const unsigned short*)p)[i]) : ((const float*)p)[i];
}
// block-parallel dtype detect (bf16 ~100% of sampled exps in [100,140]; f32 ~58%)
DEV int blk_mode(const void* x, int nt, int tid){
  const unsigned short* u = (const unsigned short*)x;
  int e = (u[tid & 255] >> 7) & 0xFF;
  int cnt = __syncthreads_count(e >= 100 && e <= 140);
  return cnt * 4 >= nt * 3;
}

// K1: h = x@W ; s = h·fcc_w ; P,Q (LDS only) ; su/sv fused (sv[r]==sv[r+64])
// 512 blocks x 4 rows, 2 blocks/CU. GEMM: thread=(cg,fq): fq owns f-quad
// (vector W load), cg owns 32-wide c-slice -> 32 vector loads/thread instead
// of 128 scalar (4x shorter latency chain); partials reduced via padded LDS.
__global__ __launch_bounds__(256, 2) void k_h_pq(const void* __restrict__ xr,
                                                 const void* __restrict__ Wp,
                                                 const void* __restrict__ Ap,
                                                 const void* __restrict__ fccwp,
                                                 const void* __restrict__ fcwp,
                                                 float* __restrict__ ws){
  int blk = blockIdx.x, tid = threadIdx.x;
  int b = blk >> 5, i0 = (blk & 31) * 4;
  __shared__ __align__(16) float xl[4*FIN];
  __shared__ __align__(16) float hrow[4*FOUT];
  __shared__ __align__(16) float pl[4*EOUT];
  __shared__ __align__(16) float ql[4*EOUT];
  __shared__ float red[16];
  __shared__ __align__(16) float red4[4*64*20];   // partials, stride 20 (bank pad)
  int mode = blk_mode(xr, 256, tid);
  if (mode){
    const unsigned short* xu = (const unsigned short*)xr + (size_t)(b*N + i0)*FIN;
    for (int t = tid; t < 4*FIN/8; t += 256){
      uint4 u4 = ((const uint4*)xu)[t];
      float* o = &xl[t*8];
      bf2x(u4.x,o[0],o[1]); bf2x(u4.y,o[2],o[3]); bf2x(u4.z,o[4],o[5]); bf2x(u4.w,o[6],o[7]);
    }
  } else {
    const float* xf = (const float*)xr + (size_t)(b*N + i0)*FIN;
    for (int t4 = tid; t4 < 4*FIN/4; t4 += 256)
      *(float4*)&xl[t4*4] = ((const float4*)xf)[t4];
  }
  __syncthreads();
  // ---- h = x@W : f-quad ownership ----
  {
    int cg = tid >> 6, fq = tid & 63;
    int c0 = cg * 32, f0 = fq * 4;
    float a4[4][4] = {{0,0,0,0},{0,0,0,0},{0,0,0,0},{0,0,0,0}};
    if (mode){
      const unsigned short* Wu = (const unsigned short*)Wp;
      #pragma unroll 4
      for (int c = c0; c < c0+32; ++c){
        uint2 wq = *(const uint2*)&Wu[c*FOUT + f0];
        float w0,w1,w2,w3; bf2x(wq.x,w0,w1); bf2x(wq.y,w2,w3);
        #pragma unroll
        for (int r = 0; r < 4; ++r){
          float xv = xl[r*FIN + c];           // wave-uniform -> LDS broadcast
          a4[r][0] += xv*w0; a4[r][1] += xv*w1;
          a4[r][2] += xv*w2; a4[r][3] += xv*w3;
        }
      }
    } else {
      const float* Wf = (const float*)Wp;
      #pragma unroll 4
      for (int c = c0; c < c0+32; ++c){
        float4 w4 = *(const float4*)&Wf[c*FOUT + f0];
        #pragma unroll
        for (int r = 0; r < 4; ++r){
          float xv = xl[r*FIN + c];
          a4[r][0] += xv*w4.x; a4[r][1] += xv*w4.y;
          a4[r][2] += xv*w4.z; a4[r][3] += xv*w4.w;
        }
      }
    }
    float* rp = &red4[(cg*64 + fq)*20];
    #pragma unroll
    for (int r = 0; r < 4; ++r)
      *(float4*)&rp[r*4] = *(const float4*)&a4[r][0];
  }
  __syncthreads();
  int f = tid;
  float acc[4];
  {
    int fq2 = f >> 2, j = f & 3;
    #pragma unroll
    for (int r = 0; r < 4; ++r){
      float s0 = red4[(0*64+fq2)*20 + r*4 + j];
      float s1 = red4[(1*64+fq2)*20 + r*4 + j];
      float s2 = red4[(2*64+fq2)*20 + r*4 + j];
      float s3 = red4[(3*64+fq2)*20 + r*4 + j];
      acc[r] = (s0+s1)+(s2+s3);
    }
  }
  float fw = ldf(fccwp, f, mode);
  #pragma unroll
  for (int r = 0; r < 4; ++r){
    ws[O_H + (b*N + i0 + r)*FOUT + f] = acc[r];
    hrow[r*FOUT + f] = acc[r];
  }
  #pragma unroll
  for (int r = 0; r < 4; ++r){
    float v = acc[r] * fw;
    for (int off = 32; off; off >>= 1) v += __shfl_down(v, off);
    if ((tid & 63) == 0) red[(tid >> 6)*4 + r] = v;
  }
  __syncthreads();
  if (tid < 4){
    float s = red[tid] + red[4+tid] + red[8+tid] + red[12+tid];
    ws[O_S + b*N + i0 + tid] = s;
  }
  // P/Q into LDS (4 waves: which = P/Q, hh = row-half); hrow reads wave-uniform
  {
    int o = tid & 63, which = (tid >> 6) & 1, hh = tid >> 7;
    float a2[2] = {0.f,0.f};
    if (mode){
      const unsigned short* Au = (const unsigned short*)Ap;
      #pragma unroll 2
      for (int c = 0; c < FOUT; c += 4){
        float w0 = bf16_to_f32(Au[(which*FOUT + c+0)*EOUT + o]);
        float w1 = bf16_to_f32(Au[(which*FOUT + c+1)*EOUT + o]);
        float w2 = bf16_to_f32(Au[(which*FOUT + c+2)*EOUT + o]);
        float w3 = bf16_to_f32(Au[(which*FOUT + c+3)*EOUT + o]);
        #pragma unroll
        for (int r = 0; r < 2; ++r){
          float4 h4 = *(const float4*)&hrow[(hh*2+r)*FOUT + c];
          a2[r] += h4.x*w0 + h4.y*w1 + h4.z*w2 + h4.w*w3;
        }
      }
    } else {
      const float* Af = (const float*)Ap;
      #pragma unroll 2
      for (int c = 0; c < FOUT; c += 4){
        float w0 = Af[(which*FOUT + c+0)*EOUT + o];
        float w1 = Af[(which*FOUT + c+1)*EOUT + o];
        float w2 = Af[(which*FOUT + c+2)*EOUT + o];
        float w3 = Af[(which*FOUT + c+3)*EOUT + o];
        #pragma unroll
        for (int r = 0; r < 2; ++r){
          float4 h4 = *(const float4*)&hrow[(hh*2+r)*FOUT + c];
          a2[r] += h4.x*w0 + h4.y*w1 + h4.z*w2 + h4.w*w3;
        }
      }
    }
    float* dst = which ? ql : pl;
    #pragma unroll
    for (int r = 0; r < 2; ++r) dst[(hh*2+r)*EOUT + o] = a2[r];
  }
  __syncthreads();
  // su for rows i0..i0+3 ; sv for pairs (value keyed by j2=(2r)&127; sv[r]==sv[r+64])
  {
    int o = tid & 63, w = tid >> 6;
    float fw2 = ldf(fcwp, o, mode);
    int w2 = (w < 2) ? w : 0;            // waves 2,3 compute a dummy s3 (not stored)
    float s1 = lrelu(pl[w*EOUT + o]        + ql[w*EOUT + o])        * fw2;
    float s3 = lrelu(pl[(2*w2)*EOUT + o]   + ql[(2*w2+1)*EOUT + o]) * fw2;
    for (int off = 32; off; off >>= 1){
      s1 += __shfl_down(s1, off); s3 += __shfl_down(s3, off);
    }
    if (o == 0){
      ws[O_SU + b*N + i0 + w] = s1;
      if (w < 2){
        int r1 = (i0 >> 1) + w;
        ws[O_SV + b*N + r1]      = s3;
        ws[O_SV + b*N + r1 + 64] = s3;
      }
    }
  }
}

struct AttArgs { const void *we,*x,*wfcw,*wfcb,*fcw,*fcb,*fccb,*wihf,*bihf,*bhhf,*wihb,*bihb,*bhhb; };

// K2: per block: TWO (b,i) rows. edge-MLP + mask + softmax -> att ; hn_pre ; z
__global__ __launch_bounds__(256) void k_att(AttArgs A, const int* __restrict__ adj,
                                             float* __restrict__ ws){
  int blk = blockIdx.x, tid = threadIdx.x;
  int half = tid >> 7, j = tid & 127, wv = (tid >> 6) & 1;
  int tau = blk*2 + half;
  int b = tau >> 7, i = tau & 127;
  __shared__ __align__(16) float wel[2][N*BINW];
  __shared__ __align__(16) float hnp[2][N];
  __shared__ __align__(16) float wfcwl[BINW*BOUT];
  __shared__ __align__(16) float wfcbl[BOUT];
  __shared__ __align__(16) float fcw2l[BOUT];
  __shared__ float red2[2][2];
  int mode = blk_mode(A.x, 256, tid);
  for (int t = tid; t < BINW*BOUT; t += 256) wfcwl[t] = ldf(A.wfcw, t, mode);
  if (tid < BOUT){ wfcbl[tid] = ldf(A.wfcb, tid, mode); fcw2l[tid] = ldf(A.fcw, EOUT + tid, mode); }
  if (mode){
    const unsigned short* weu = (const unsigned short*)A.we + (size_t)(b*N + i)*N*BINW;
    for (int t = j; t < N*BINW/8; t += 128){
      uint4 q = ((const uint4*)weu)[t];
      float* o = &wel[half][t*8];
      bf2x(q.x,o[0],o[1]); bf2x(q.y,o[2],o[3]); bf2x(q.z,o[4],o[5]); bf2x(q.w,o[6],o[7]);
    }
  } else {
    const float* wef = (const float*)A.we + (size_t)(b*N + i)*N*BINW;
    for (int t4 = j; t4 < N*BINW/4; t4 += 128)
      *(float4*)&wel[half][t4*4] = ((const float4*)wef)[t4];
  }
  __syncthreads();
  float wr[BINW];
  #pragma unroll
  for (int t = 0; t < BINW; ++t) wr[t] = wel[half][j*BINW + t];
  float wcon = 0.f;
  for (int o = 0; o < BOUT; o += 4){
    float4 bb = *(const float4*)&wfcbl[o];
    float w0 = bb.x, w1 = bb.y, w2 = bb.z, w3 = bb.w;
    #pragma unroll
    for (int t = 0; t < BINW; ++t){
      float4 w4 = *(const float4*)&wfcwl[t*BOUT + o];
      w0 = fmaf(wr[t], w4.x, w0); w1 = fmaf(wr[t], w4.y, w1);
      w2 = fmaf(wr[t], w4.z, w2); w3 = fmaf(wr[t], w4.w, w3);
    }
    float4 f4 = *(const float4*)&fcw2l[o];
    wcon += lrelu(w0)*f4.x + lrelu(w1)*f4.y + lrelu(w2)*f4.z + lrelu(w3)*f4.w;
  }
  const float* R = ws;
  float econ = (i < 64) ? R[O_SU + b*N + 2*i + (j >= 64 ? 1 : 0)]
                        : R[O_SV + b*N + j];
  float etot = econ + wcon + ldf(A.fcb, 0, mode);
  float m = (adj[(b*N + i)*N + j] > 0) ? etot : -9e15f;
  float mx = m;
  for (int off = 32; off; off >>= 1) mx = fmaxf(mx, __shfl_xor(mx, off));
  if ((tid & 63) == 0) red2[half][wv] = mx;
  __syncthreads();
  mx = fmaxf(red2[half][0], red2[half][1]);
  float ev = expf(m - mx);
  float sum = ev;
  for (int off = 32; off; off >>= 1) sum += __shfl_xor(sum, off);
  __syncthreads();
  if ((tid & 63) == 0) red2[half][wv] = sum;
  __syncthreads();
  sum = red2[half][0] + red2[half][1];
  float att = ev / sum;
  ws[O_ATT + (b*N + i)*N + j] = att;
  float sbi = R[O_S + b*N + i];
  hnp[half][j] = lrelu(att * sbi + ldf(A.fccb, 0, mode));
  __syncthreads();
  // z[b,i,c] both directions (per half: 2 waves = 2 directions)
  {
    int d = wv, c = tid & 63;
    float acc = ldf(d ? A.bihb : A.bihf, c, mode) + ldf(d ? A.bhhb : A.bhhf, c, mode);
    const void* wihp = d ? A.wihb : A.wihf;
    if (mode){
      const uint4* wq = (const uint4*)((const unsigned short*)wihp + c*N);
      #pragma unroll 4
      for (int k = 0; k < N; k += 8){
        uint4 q = wq[k >> 3];
        float w0,w1,w2,w3,w4,w5,w6,w7;
        bf2x(q.x,w0,w1); bf2x(q.y,w2,w3); bf2x(q.z,w4,w5); bf2x(q.w,w6,w7);
        float4 h0 = *(const float4*)&hnp[half][k];
        float4 h1 = *(const float4*)&hnp[half][k+4];
        acc += h0.x*w0 + h0.y*w1 + h0.z*w2 + h0.w*w3
             + h1.x*w4 + h1.y*w5 + h1.z*w6 + h1.w*w7;
      }
    } else {
      const float* wf = (const float*)wihp + c*N;
      #pragma unroll 8
      for (int k = 0; k < N; k += 4){
        float4 h4 = *(const float4*)&hnp[half][k];
        float4 w4 = *(const float4*)&wf[k];
        acc += h4.x*w4.x + h4.y*w4.y + h4.z*w4.z + h4.w*w4.w;
      }
    }
    ws[(d ? O_ZB : O_ZF) + (b*N + i)*CI + c] = acc;
  }
}

// K3: blocks 0..31: serial RNN chains (wave 0).
//     blocks 32..543: h1 = att@h (4 rows) FUSED with partial = h1@fco_w[2CI:,:]+fco_b.
// The partial GEMM (2/3 of old K4's work) hides under the RNN chains' latency.
__global__ __launch_bounds__(256, 1) void k_rnn_h1(const void* __restrict__ xr,
                                                   const void* __restrict__ whhf,
                                                   const void* __restrict__ whhb,
                                                   const void* __restrict__ fcowp,
                                                   const void* __restrict__ fcobp,
                                                   float* __restrict__ ws){
  __shared__ __align__(16) float sh[N*CI];   // rnn: 32 KB; h1: attT (512) + h1 rows (1024)
  int blk = blockIdx.x, tid = threadIdx.x;
  int mode = blk_mode(xr, 256, tid);
  const float* R = ws;
  if (blk < 32){
    int d = blk >> 4, b = blk & 15;
    const int zb = (d ? O_ZB : O_ZF) + b*N*CI;
    const int ob = (d ? O_RB : O_RF) + b*N*CI;
    for (int it = tid; it < N*CI/4; it += 256)
      *(float4*)&sh[it*4] = *(const float4*)&ws[zb + it*4];
    __syncthreads();
    if (tid < 64){
      int c = tid;
      const void* whhp = d ? whhb : whhf;
      float wreg[CI];
      if (mode){
        const uint4* wq = (const uint4*)((const unsigned short*)whhp + c*CI);
        #pragma unroll
        for (int k = 0; k < CI; k += 8){
          uint4 q = wq[k >> 3];
          bf2x(q.x,wreg[k+0],wreg[k+1]); bf2x(q.y,wreg[k+2],wreg[k+3]);
          bf2x(q.z,wreg[k+4],wreg[k+5]); bf2x(q.w,wreg[k+6],wreg[k+7]);
        }
      } else {
        const float* wf = (const float*)whhp + c*CI;
        #pragma unroll
        for (int k = 0; k < CI; k += 4){
          float4 w4 = *(const float4*)&wf[k];
          wreg[k]=w4.x; wreg[k+1]=w4.y; wreg[k+2]=w4.z; wreg[k+3]=w4.w;
        }
      }
      const int step = d ? -1 : 1;
      int tt = d ? (N-1) : 0;
      float hv = 0.f;
      float z = sh[tt*CI + c];    // single wave: DS ops in-order, no barrier needed
      for (int t = 0; t < N; ++t){
        int ti = tt + step; ti = ti < 0 ? 0 : (ti > N-1 ? N-1 : ti);
        float znext = sh[ti*CI + c];
        float s[CI];
        #pragma unroll
        for (int k = 0; k < CI; ++k) s[k] = bcastf(hv, k);   // batched readlanes
#if __has_builtin(__builtin_amdgcn_sched_barrier)
        __builtin_amdgcn_sched_barrier(0);
#endif
        float a0 = z, a1 = 0.f, a2 = 0.f, a3 = 0.f;
        #pragma unroll
        for (int k = 0; k < CI; k += 4){
          a0 = fmaf(s[k+0], wreg[k+0], a0);
          a1 = fmaf(s[k+1], wreg[k+1], a1);
          a2 = fmaf(s[k+2], wreg[k+2], a2);
          a3 = fmaf(s[k+3], wreg[k+3], a3);
        }
        float x = (a0+a1)+(a2+a3);
        x = fminf(15.f, fmaxf(-15.f, x));
        float p = __expf(2.f * x);
        hv = (p - 1.f) * __builtin_amdgcn_rcpf(p + 1.f);
        sh[tt*CI + c] = hv;
        z = znext;
        tt += step;
      }
    }
    __syncthreads();
    for (int it = tid; it < N*CI/4; it += 256)
      *(float4*)&ws[ob + it*4] = *(const float4*)&sh[it*4];
  } else {
    int task = blk - 32;                 // 0..511, 4 rows each
    int b = task >> 5, i0 = (task & 31) * 4;
    int f = tid;
    for (int t = tid; t < 4*N; t += 256){
      int r = t >> 7, k = t & 127;
      sh[k*4 + r] = R[O_ATT + (b*N + i0 + r)*N + k];
    }
    __syncthreads();
    float acc[4] = {0,0,0,0};
    #pragma unroll 4
    for (int k = 0; k < N; ++k){
      float hv = R[O_H + (b*N + k)*FOUT + f];
      float4 a0 = *(const float4*)&sh[k*4];
      acc[0] += a0.x*hv; acc[1] += a0.y*hv; acc[2] += a0.z*hv; acc[3] += a0.w*hv;
    }
    // h1 rows -> LDS, then partial = h1 @ fco_w[2CI:,:] + fco_b  (hidden under RNN)
    float* h1l = sh + 4*N;     // 1024 floats
    #pragma unroll
    for (int r = 0; r < 4; ++r) h1l[r*FOUT + f] = acc[r];
    __syncthreads();
    float bias = ldf(fcobp, f, mode);
    float p4[4] = {bias, bias, bias, bias};
    if (mode){
      const unsigned short* fu = (const unsigned short*)fcowp + (size_t)(2*CI)*L1;
      #pragma unroll 2
      for (int k = 0; k < FOUT; k += 4){
        float w0 = bf16_to_f32(fu[(k+0)*L1 + f]);
        float w1 = bf16_to_f32(fu[(k+1)*L1 + f]);
        float w2 = bf16_to_f32(fu[(k+2)*L1 + f]);
        float w3 = bf16_to_f32(fu[(k+3)*L1 + f]);
        #pragma unroll
        for (int r = 0; r < 4; ++r){
          float4 hv = *(const float4*)&h1l[r*FOUT + k];   // wave-uniform -> LDS broadcast
          p4[r] += hv.x*w0 + hv.y*w1 + hv.z*w2 + hv.w*w3;
        }
      }
    } else {
      const float* ff = (const float*)fcowp + (size_t)(2*CI)*L1;
      #pragma unroll 2
      for (int k = 0; k < FOUT; k += 4){
        float w0 = ff[(k+0)*L1 + f];
        float w1 = ff[(k+1)*L1 + f];
        float w2 = ff[(k+2)*L1 + f];
        float w3 = ff[(k+3)*L1 + f];
        #pragma unroll
        for (int r = 0; r < 4; ++r){
          float4 hv = *(const float4*)&h1l[r*FOUT + k];
          p4[r] += hv.x*w0 + hv.y*w1 + hv.z*w2 + hv.w*w3;
        }
      }
    }
    #pragma unroll
    for (int r = 0; r < 4; ++r)
      ws[O_H1 + (b*N + i0 + r)*L1 + f] = p4[r];
  }
}

// K4 (thin): out = elu(partial + cat(lrelu(rf),lrelu(rb)) @ fco_w[0:2CI,:])
__global__ __launch_bounds__(256, 2) void k_out(const void* __restrict__ xr,
                                                const void* __restrict__ fcowp,
                                                const float* __restrict__ R, void* dout){
  int blk = blockIdx.x, tid = threadIdx.x;
  int b = blk >> 5, i0 = (blk & 31) * 4;
  __shared__ __align__(16) float inl[4*2*CI];   // 4 rows x 128
  int mode = blk_mode(xr, 256, tid);
  for (int t = tid; t < 4*2*CI; t += 256){
    int r = t >> 7, k = t & 127;
    int row = b*N + i0 + r;
    inl[r*128 + k] = (k < CI) ? lrelu(R[O_RF + row*CI + k])
                              : lrelu(R[O_RB + row*CI + (k - CI)]);
  }
  __syncthreads();
  int l = tid;
  float acc[4];
  #pragma unroll
  for (int r = 0; r < 4; ++r) acc[r] = R[O_H1 + (b*N + i0 + r)*L1 + l];  // partial (incl bias+h1 part)
  if (mode){
    const unsigned short* fu = (const unsigned short*)fcowp;
    #pragma unroll 4
    for (int k = 0; k < 2*CI; k += 4){
      float w0 = bf16_to_f32(fu[(k+0)*L1 + l]);
      float w1 = bf16_to_f32(fu[(k+1)*L1 + l]);
      float w2 = bf16_to_f32(fu[(k+2)*L1 + l]);
      float w3 = bf16_to_f32(fu[(k+3)*L1 + l]);
      #pragma unroll
      for (int r = 0; r < 4; ++r){
        float4 v = *(const float4*)&inl[r*128 + k];
        acc[r] += v.x*w0 + v.y*w1 + v.z*w2 + v.w*w3;
      }
    }
  } else {
    const float* ff = (const float*)fcowp;
    #pragma unroll 4
    for (int k = 0; k < 2*CI; k += 4){
      float w0 = ff[(k+0)*L1 + l];
      float w1 = ff[(k+1)*L1 + l];
      float w2 = ff[(k+2)*L1 + l];
      float w3 = ff[(k+3)*L1 + l];
      #pragma unroll
      for (int r = 0; r < 4; ++r){
        float4 v = *(const float4*)&inl[r*128 + k];
        acc[r] += v.x*w0 + v.y*w1 + v.z*w2 + v.w*w3;
      }
    }
  }
  #pragma unroll
  for (int r = 0; r < 4; ++r){
    float o = acc[r] > 0.f ? acc[r] : expm1f(acc[r]);
    int idx = (b*N + i0 + r)*L1 + l;
    if (mode) ((__hip_bfloat16*)dout)[idx] = __float2bfloat16(o);
    else      ((float*)dout)[idx] = o;
  }
}

extern "C" void kernel_launch(void* const* d_in, const int* in_sizes, int n_in,
                              void* d_out, int out_size, void* d_ws, size_t ws_size,
                              hipStream_t stream){
  (void)in_sizes; (void)n_in; (void)out_size; (void)ws_size;
  float* ws = (float*)d_ws;
  AttArgs A;
  A.we = d_in[2]; A.x = d_in[0]; A.wfcw = d_in[5]; A.wfcb = d_in[6];
  A.fcw = d_in[7]; A.fcb = d_in[8]; A.fccb = d_in[10];
  A.wihf = d_in[11]; A.bihf = d_in[13]; A.bhhf = d_in[14];
  A.wihb = d_in[15]; A.bihb = d_in[17]; A.bhhb = d_in[18];
  hipLaunchKernelGGL(k_h_pq,   dim3(512),    dim3(256), 0, stream,
                     d_in[0], d_in[3], d_in[4], d_in[9], d_in[7], ws);
  hipLaunchKernelGGL(k_att,    dim3(B*N/2),  dim3(256), 0, stream, A, (const int*)d_in[1], ws);
  hipLaunchKernelGGL(k_rnn_h1, dim3(544),    dim3(256), 0, stream,
                     d_in[0], d_in[12], d_in[16], d_in[19], d_in[20], ws);
  hipLaunchKernelGGL(k_out,    dim3(512),    dim3(256), 0, stream,
                     d_in[0], d_in[19], ws, d_out);
}

// Round 7
// 188.101 us; speedup vs baseline: 1.0629x; 1.0231x over previous
//
#include <hip/hip_runtime.h>
#include <hip/hip_bf16.h>

#define DEV static __device__ __forceinline__

constexpr int B=16, N=128, FIN=128, FOUT=256, EOUT=64, BINW=14, BOUT=64, CI=64, L1=256;

// ---- scratch layout in d_ws (float offsets) ----
constexpr int O_H   = 0;                       // [B,N,FOUT]
constexpr int O_S   = O_H  + B*N*FOUT;         // [B,N]
constexpr int O_SU  = O_S  + B*N;
constexpr int O_SV  = O_SU + B*N;
constexpr int O_ATT = O_SV + B*N;              // [B,N,N]
constexpr int O_ZF  = O_ATT+ B*N*N;            // [B,N,CI]
constexpr int O_ZB  = O_ZF + B*N*CI;
constexpr int O_RF  = O_ZB + B*N*CI;
constexpr int O_RB  = O_RF + B*N*CI;
constexpr int O_H1  = O_RB + B*N*CI;           // [B,N,L1] : partial = h1@fco_w[2CI:,:] + fco_b

DEV float bf16_to_f32(unsigned short u){
  unsigned int x = ((unsigned int)u) << 16; float f;
  __builtin_memcpy(&f, &x, 4); return f;
}
DEV void bf2x(unsigned int u, float& lo, float& hi){
  unsigned int a = u << 16, b = u & 0xFFFF0000u;
  __builtin_memcpy(&lo, &a, 4); __builtin_memcpy(&hi, &b, 4);
}
DEV float lrelu(float x){ return x > 0.f ? x : 0.01f * x; }
DEV float bcastf(float v, int lane){
  return __builtin_bit_cast(float, __builtin_amdgcn_readlane(__builtin_bit_cast(int, v), lane));
}
DEV float ldf(const void* p, int i, int m){
  return m ? bf16_to_f32(((const unsigned short*)p)[i]) : ((const float*)p)[i];
}
// block-parallel dtype detect (bf16 ~100% of sampled exps in [100,140]; f32 ~58%)
DEV int blk_mode(const void* x, int nt, int tid){
  const unsigned short* u = (const unsigned short*)x;
  int e = (u[tid & 255] >> 7) & 0xFF;
  int cnt = __syncthreads_count(e >= 100 && e <= 140);
  return cnt * 4 >= nt * 3;
}

// K1: h = x@W ; s = h·fcc_w ; P,Q (LDS only) ; su/sv fused (sv[r]==sv[r+64])
// 512 blocks x 4 rows, 2 blocks/CU. GEMM: thread=(cg,fq): fq owns f-quad
// (vector W load), cg owns 32-wide c-slice -> 32 vector loads/thread instead
// of 128 scalar (4x shorter latency chain); partials reduced via padded LDS.
__global__ __launch_bounds__(256, 2) void k_h_pq(const void* __restrict__ xr,
                                                 const void* __restrict__ Wp,
                                                 const void* __restrict__ Ap,
                                                 const void* __restrict__ fccwp,
                                                 const void* __restrict__ fcwp,
                                                 float* __restrict__ ws){
  int blk = blockIdx.x, tid = threadIdx.x;
  int b = blk >> 5, i0 = (blk & 31) * 4;
  __shared__ __align__(16) float xl[4*FIN];
  __shared__ __align__(16) float hrow[4*FOUT];
  __shared__ __align__(16) float pl[4*EOUT];
  __shared__ __align__(16) float ql[4*EOUT];
  __shared__ float red[16];
  __shared__ __align__(16) float red4[4*64*20];   // partials, stride 20 (bank pad)
  int mode = blk_mode(xr, 256, tid);
  if (mode){
    const unsigned short* xu = (const unsigned short*)xr + (size_t)(b*N + i0)*FIN;
    for (int t = tid; t < 4*FIN/8; t += 256){
      uint4 u4 = ((const uint4*)xu)[t];
      float* o = &xl[t*8];
      bf2x(u4.x,o[0],o[1]); bf2x(u4.y,o[2],o[3]); bf2x(u4.z,o[4],o[5]); bf2x(u4.w,o[6],o[7]);
    }
  } else {
    const float* xf = (const float*)xr + (size_t)(b*N + i0)*FIN;
    for (int t4 = tid; t4 < 4*FIN/4; t4 += 256)
      *(float4*)&xl[t4*4] = ((const float4*)xf)[t4];
  }
  __syncthreads();
  // ---- h = x@W : f-quad ownership ----
  {
    int cg = tid >> 6, fq = tid & 63;
    int c0 = cg * 32, f0 = fq * 4;
    float a4[4][4] = {{0,0,0,0},{0,0,0,0},{0,0,0,0},{0,0,0,0}};
    if (mode){
      const unsigned short* Wu = (const unsigned short*)Wp;
      #pragma unroll 4
      for (int c = c0; c < c0+32; ++c){
        uint2 wq = *(const uint2*)&Wu[c*FOUT + f0];
        float w0,w1,w2,w3; bf2x(wq.x,w0,w1); bf2x(wq.y,w2,w3);
        #pragma unroll
        for (int r = 0; r < 4; ++r){
          float xv = xl[r*FIN + c];           // wave-uniform -> LDS broadcast
          a4[r][0] += xv*w0; a4[r][1] += xv*w1;
          a4[r][2] += xv*w2; a4[r][3] += xv*w3;
        }
      }
    } else {
      const float* Wf = (const float*)Wp;
      #pragma unroll 4
      for (int c = c0; c < c0+32; ++c){
        float4 w4 = *(const float4*)&Wf[c*FOUT + f0];
        #pragma unroll
        for (int r = 0; r < 4; ++r){
          float xv = xl[r*FIN + c];
          a4[r][0] += xv*w4.x; a4[r][1] += xv*w4.y;
          a4[r][2] += xv*w4.z; a4[r][3] += xv*w4.w;
        }
      }
    }
    float* rp = &red4[(cg*64 + fq)*20];
    #pragma unroll
    for (int r = 0; r < 4; ++r)
      *(float4*)&rp[r*4] = *(const float4*)&a4[r][0];
  }
  __syncthreads();
  int f = tid;
  float acc[4];
  {
    int fq2 = f >> 2, j = f & 3;
    #pragma unroll
    for (int r = 0; r < 4; ++r){
      float s0 = red4[(0*64+fq2)*20 + r*4 + j];
      float s1 = red4[(1*64+fq2)*20 + r*4 + j];
      float s2 = red4[(2*64+fq2)*20 + r*4 + j];
      float s3 = red4[(3*64+fq2)*20 + r*4 + j];
      acc[r] = (s0+s1)+(s2+s3);
    }
  }
  float fw = ldf(fccwp, f, mode);
  #pragma unroll
  for (int r = 0; r < 4; ++r){
    ws[O_H + (b*N + i0 + r)*FOUT + f] = acc[r];
    hrow[r*FOUT + f] = acc[r];
  }
  #pragma unroll
  for (int r = 0; r < 4; ++r){
    float v = acc[r] * fw;
    for (int off = 32; off; off >>= 1) v += __shfl_down(v, off);
    if ((tid & 63) == 0) red[(tid >> 6)*4 + r] = v;
  }
  __syncthreads();
  if (tid < 4){
    float s = red[tid] + red[4+tid] + red[8+tid] + red[12+tid];
    ws[O_S + b*N + i0 + tid] = s;
  }
  // P/Q into LDS (4 waves: which = P/Q, hh = row-half); hrow reads wave-uniform
  {
    int o = tid & 63, which = (tid >> 6) & 1, hh = tid >> 7;
    float a2[2] = {0.f,0.f};
    if (mode){
      const unsigned short* Au = (const unsigned short*)Ap;
      #pragma unroll 2
      for (int c = 0; c < FOUT; c += 4){
        float w0 = bf16_to_f32(Au[(which*FOUT + c+0)*EOUT + o]);
        float w1 = bf16_to_f32(Au[(which*FOUT + c+1)*EOUT + o]);
        float w2 = bf16_to_f32(Au[(which*FOUT + c+2)*EOUT + o]);
        float w3 = bf16_to_f32(Au[(which*FOUT + c+3)*EOUT + o]);
        #pragma unroll
        for (int r = 0; r < 2; ++r){
          float4 h4 = *(const float4*)&hrow[(hh*2+r)*FOUT + c];
          a2[r] += h4.x*w0 + h4.y*w1 + h4.z*w2 + h4.w*w3;
        }
      }
    } else {
      const float* Af = (const float*)Ap;
      #pragma unroll 2
      for (int c = 0; c < FOUT; c += 4){
        float w0 = Af[(which*FOUT + c+0)*EOUT + o];
        float w1 = Af[(which*FOUT + c+1)*EOUT + o];
        float w2 = Af[(which*FOUT + c+2)*EOUT + o];
        float w3 = Af[(which*FOUT + c+3)*EOUT + o];
        #pragma unroll
        for (int r = 0; r < 2; ++r){
          float4 h4 = *(const float4*)&hrow[(hh*2+r)*FOUT + c];
          a2[r] += h4.x*w0 + h4.y*w1 + h4.z*w2 + h4.w*w3;
        }
      }
    }
    float* dst = which ? ql : pl;
    #pragma unroll
    for (int r = 0; r < 2; ++r) dst[(hh*2+r)*EOUT + o] = a2[r];
  }
  __syncthreads();
  // su for rows i0..i0+3 ; sv for pairs (value keyed by j2=(2r)&127; sv[r]==sv[r+64])
  {
    int o = tid & 63, w = tid >> 6;
    float fw2 = ldf(fcwp, o, mode);
    int w2 = (w < 2) ? w : 0;            // waves 2,3 compute a dummy s3 (not stored)
    float s1 = lrelu(pl[w*EOUT + o]        + ql[w*EOUT + o])        * fw2;
    float s3 = lrelu(pl[(2*w2)*EOUT + o]   + ql[(2*w2+1)*EOUT + o]) * fw2;
    for (int off = 32; off; off >>= 1){
      s1 += __shfl_down(s1, off); s3 += __shfl_down(s3, off);
    }
    if (o == 0){
      ws[O_SU + b*N + i0 + w] = s1;
      if (w < 2){
        int r1 = (i0 >> 1) + w;
        ws[O_SV + b*N + r1]      = s3;
        ws[O_SV + b*N + r1 + 64] = s3;
      }
    }
  }
}

struct AttArgs { const void *we,*x,*wfcw,*wfcb,*fcw,*fcb,*fccb,*wihf,*bihf,*bhhf,*wihb,*bihb,*bhhb; };

// K2: per block: TWO (b,i) rows. edge-MLP + mask + softmax -> att ; hn_pre ; z
__global__ __launch_bounds__(256) void k_att(AttArgs A, const int* __restrict__ adj,
                                             float* __restrict__ ws){
  int blk = blockIdx.x, tid = threadIdx.x;
  int half = tid >> 7, j = tid & 127, wv = (tid >> 6) & 1;
  int tau = blk*2 + half;
  int b = tau >> 7, i = tau & 127;
  __shared__ __align__(16) float wel[2][N*BINW];
  __shared__ __align__(16) float hnp[2][N];
  __shared__ __align__(16) float wfcwl[BINW*BOUT];
  __shared__ __align__(16) float wfcbl[BOUT];
  __shared__ __align__(16) float fcw2l[BOUT];
  __shared__ float red2[2][2];
  int mode = blk_mode(A.x, 256, tid);
  for (int t = tid; t < BINW*BOUT; t += 256) wfcwl[t] = ldf(A.wfcw, t, mode);
  if (tid < BOUT){ wfcbl[tid] = ldf(A.wfcb, tid, mode); fcw2l[tid] = ldf(A.fcw, EOUT + tid, mode); }
  if (mode){
    const unsigned short* weu = (const unsigned short*)A.we + (size_t)(b*N + i)*N*BINW;
    for (int t = j; t < N*BINW/8; t += 128){
      uint4 q = ((const uint4*)weu)[t];
      float* o = &wel[half][t*8];
      bf2x(q.x,o[0],o[1]); bf2x(q.y,o[2],o[3]); bf2x(q.z,o[4],o[5]); bf2x(q.w,o[6],o[7]);
    }
  } else {
    const float* wef = (const float*)A.we + (size_t)(b*N + i)*N*BINW;
    for (int t4 = j; t4 < N*BINW/4; t4 += 128)
      *(float4*)&wel[half][t4*4] = ((const float4*)wef)[t4];
  }
  __syncthreads();
  float wr[BINW];
  #pragma unroll
  for (int t = 0; t < BINW; ++t) wr[t] = wel[half][j*BINW + t];
  float wcon = 0.f;
  for (int o = 0; o < BOUT; o += 4){
    float4 bb = *(const float4*)&wfcbl[o];
    float w0 = bb.x, w1 = bb.y, w2 = bb.z, w3 = bb.w;
    #pragma unroll
    for (int t = 0; t < BINW; ++t){
      float4 w4 = *(const float4*)&wfcwl[t*BOUT + o];
      w0 = fmaf(wr[t], w4.x, w0); w1 = fmaf(wr[t], w4.y, w1);
      w2 = fmaf(wr[t], w4.z, w2); w3 = fmaf(wr[t], w4.w, w3);
    }
    float4 f4 = *(const float4*)&fcw2l[o];
    wcon += lrelu(w0)*f4.x + lrelu(w1)*f4.y + lrelu(w2)*f4.z + lrelu(w3)*f4.w;
  }
  const float* R = ws;
  float econ = (i < 64) ? R[O_SU + b*N + 2*i + (j >= 64 ? 1 : 0)]
                        : R[O_SV + b*N + j];
  float etot = econ + wcon + ldf(A.fcb, 0, mode);
  float m = (adj[(b*N + i)*N + j] > 0) ? etot : -9e15f;
  float mx = m;
  for (int off = 32; off; off >>= 1) mx = fmaxf(mx, __shfl_xor(mx, off));
  if ((tid & 63) == 0) red2[half][wv] = mx;
  __syncthreads();
  mx = fmaxf(red2[half][0], red2[half][1]);
  float ev = expf(m - mx);
  float sum = ev;
  for (int off = 32; off; off >>= 1) sum += __shfl_xor(sum, off);
  __syncthreads();
  if ((tid & 63) == 0) red2[half][wv] = sum;
  __syncthreads();
  sum = red2[half][0] + red2[half][1];
  float att = ev / sum;
  ws[O_ATT + (b*N + i)*N + j] = att;
  float sbi = R[O_S + b*N + i];
  hnp[half][j] = lrelu(att * sbi + ldf(A.fccb, 0, mode));
  __syncthreads();
  // z[b,i,c] both directions (per half: 2 waves = 2 directions)
  {
    int d = wv, c = tid & 63;
    float acc = ldf(d ? A.bihb : A.bihf, c, mode) + ldf(d ? A.bhhb : A.bhhf, c, mode);
    const void* wihp = d ? A.wihb : A.wihf;
    if (mode){
      const uint4* wq = (const uint4*)((const unsigned short*)wihp + c*N);
      #pragma unroll 4
      for (int k = 0; k < N; k += 8){
        uint4 q = wq[k >> 3];
        float w0,w1,w2,w3,w4,w5,w6,w7;
        bf2x(q.x,w0,w1); bf2x(q.y,w2,w3); bf2x(q.z,w4,w5); bf2x(q.w,w6,w7);
        float4 h0 = *(const float4*)&hnp[half][k];
        float4 h1 = *(const float4*)&hnp[half][k+4];
        acc += h0.x*w0 + h0.y*w1 + h0.z*w2 + h0.w*w3
             + h1.x*w4 + h1.y*w5 + h1.z*w6 + h1.w*w7;
      }
    } else {
      const float* wf = (const float*)wihp + c*N;
      #pragma unroll 8
      for (int k = 0; k < N; k += 4){
        float4 h4 = *(const float4*)&hnp[half][k];
        float4 w4 = *(const float4*)&wf[k];
        acc += h4.x*w4.x + h4.y*w4.y + h4.z*w4.z + h4.w*w4.w;
      }
    }
    ws[(d ? O_ZB : O_ZF) + (b*N + i)*CI + c] = acc;
  }
}

// K3: blocks 0..31: serial RNN chains (wave 0).
//     blocks 32..543: h1 = att@h (4 rows) FUSED with partial = h1@fco_w[2CI:,:]+fco_b.
// Partial GEMM uses l-quad ownership: 64 vector loads/thread instead of 256 scalar.
__global__ __launch_bounds__(256, 1) void k_rnn_h1(const void* __restrict__ xr,
                                                   const void* __restrict__ whhf,
                                                   const void* __restrict__ whhb,
                                                   const void* __restrict__ fcowp,
                                                   const void* __restrict__ fcobp,
                                                   float* __restrict__ ws){
  __shared__ __align__(16) float sh[N*CI];   // rnn: 32 KB; h1: attT(512)+h1l(1024)+red4(5120)
  int blk = blockIdx.x, tid = threadIdx.x;
  int mode = blk_mode(xr, 256, tid);
  const float* R = ws;
  if (blk < 32){
    int d = blk >> 4, b = blk & 15;
    const int zb = (d ? O_ZB : O_ZF) + b*N*CI;
    const int ob = (d ? O_RB : O_RF) + b*N*CI;
    for (int it = tid; it < N*CI/4; it += 256)
      *(float4*)&sh[it*4] = *(const float4*)&ws[zb + it*4];
    __syncthreads();
    if (tid < 64){
      int c = tid;
      const void* whhp = d ? whhb : whhf;
      float wreg[CI];
      if (mode){
        const uint4* wq = (const uint4*)((const unsigned short*)whhp + c*CI);
        #pragma unroll
        for (int k = 0; k < CI; k += 8){
          uint4 q = wq[k >> 3];
          bf2x(q.x,wreg[k+0],wreg[k+1]); bf2x(q.y,wreg[k+2],wreg[k+3]);
          bf2x(q.z,wreg[k+4],wreg[k+5]); bf2x(q.w,wreg[k+6],wreg[k+7]);
        }
      } else {
        const float* wf = (const float*)whhp + c*CI;
        #pragma unroll
        for (int k = 0; k < CI; k += 4){
          float4 w4 = *(const float4*)&wf[k];
          wreg[k]=w4.x; wreg[k+1]=w4.y; wreg[k+2]=w4.z; wreg[k+3]=w4.w;
        }
      }
      const int step = d ? -1 : 1;
      int tt = d ? (N-1) : 0;
      float hv = 0.f;
      float z = sh[tt*CI + c];    // single wave: DS ops in-order, no barrier needed
      for (int t = 0; t < N; ++t){
        int ti = tt + step; ti = ti < 0 ? 0 : (ti > N-1 ? N-1 : ti);
        float znext = sh[ti*CI + c];
        float s[CI];
        #pragma unroll
        for (int k = 0; k < CI; ++k) s[k] = bcastf(hv, k);   // batched readlanes
#if __has_builtin(__builtin_amdgcn_sched_barrier)
        __builtin_amdgcn_sched_barrier(0);
#endif
        float a0 = z, a1 = 0.f, a2 = 0.f, a3 = 0.f;
        #pragma unroll
        for (int k = 0; k < CI; k += 4){
          a0 = fmaf(s[k+0], wreg[k+0], a0);
          a1 = fmaf(s[k+1], wreg[k+1], a1);
          a2 = fmaf(s[k+2], wreg[k+2], a2);
          a3 = fmaf(s[k+3], wreg[k+3], a3);
        }
        float x = (a0+a1)+(a2+a3);
        x = fminf(15.f, fmaxf(-15.f, x));
        float p = __expf(2.f * x);
        hv = (p - 1.f) * __builtin_amdgcn_rcpf(p + 1.f);
        sh[tt*CI + c] = hv;
        z = znext;
        tt += step;
      }
    }
    __syncthreads();
    for (int it = tid; it < N*CI/4; it += 256)
      *(float4*)&ws[ob + it*4] = *(const float4*)&sh[it*4];
  } else {
    int task = blk - 32;                 // 0..511, 4 rows each
    int b = task >> 5, i0 = (task & 31) * 4;
    int f = tid;
    float* attT = sh;                    // 512
    float* h1l  = sh + 512;              // 1024
    float* red4 = sh + 1536;             // 4*64*20 = 5120
    for (int t = tid; t < 4*N; t += 256){
      int r = t >> 7, k = t & 127;
      attT[k*4 + r] = R[O_ATT + (b*N + i0 + r)*N + k];
    }
    __syncthreads();
    float acc[4] = {0,0,0,0};
    #pragma unroll 4
    for (int k = 0; k < N; ++k){
      float hv = R[O_H + (b*N + k)*FOUT + f];
      float4 a0 = *(const float4*)&attT[k*4];
      acc[0] += a0.x*hv; acc[1] += a0.y*hv; acc[2] += a0.z*hv; acc[3] += a0.w*hv;
    }
    #pragma unroll
    for (int r = 0; r < 4; ++r) h1l[r*FOUT + f] = acc[r];
    __syncthreads();
    // partial = h1 @ fco_w[2CI:,:] : l-quad ownership (64 vector loads/thread)
    {
      int cg = tid >> 6, lq = tid & 63;
      int c0 = cg * 64, l0 = lq * 4;
      float p44[4][4] = {{0,0,0,0},{0,0,0,0},{0,0,0,0},{0,0,0,0}};
      if (mode){
        const unsigned short* fu = (const unsigned short*)fcowp + (size_t)(2*CI)*L1;
        #pragma unroll 4
        for (int c = c0; c < c0+64; ++c){
          uint2 wq = *(const uint2*)&fu[c*L1 + l0];
          float w0,w1,w2,w3; bf2x(wq.x,w0,w1); bf2x(wq.y,w2,w3);
          #pragma unroll
          for (int r = 0; r < 4; ++r){
            float hv = h1l[r*FOUT + c];        // wave-uniform -> LDS broadcast
            p44[r][0] += hv*w0; p44[r][1] += hv*w1;
            p44[r][2] += hv*w2; p44[r][3] += hv*w3;
          }
        }
      } else {
        const float* ff = (const float*)fcowp + (size_t)(2*CI)*L1;
        #pragma unroll 4
        for (int c = c0; c < c0+64; ++c){
          float4 w4 = *(const float4*)&ff[c*L1 + l0];
          #pragma unroll
          for (int r = 0; r < 4; ++r){
            float hv = h1l[r*FOUT + c];
            p44[r][0] += hv*w4.x; p44[r][1] += hv*w4.y;
            p44[r][2] += hv*w4.z; p44[r][3] += hv*w4.w;
          }
        }
      }
      float* rp = &red4[(cg*64 + lq)*20];
      #pragma unroll
      for (int r = 0; r < 4; ++r)
        *(float4*)&rp[r*4] = *(const float4*)&p44[r][0];
    }
    __syncthreads();
    {
      int fq2 = f >> 2, j = f & 3;
      float bias = ldf(fcobp, f, mode);
      #pragma unroll
      for (int r = 0; r < 4; ++r){
        float s0 = red4[(0*64+fq2)*20 + r*4 + j];
        float s1 = red4[(1*64+fq2)*20 + r*4 + j];
        float s2 = red4[(2*64+fq2)*20 + r*4 + j];
        float s3 = red4[(3*64+fq2)*20 + r*4 + j];
        ws[O_H1 + (b*N + i0 + r)*L1 + f] = bias + (s0+s1)+(s2+s3);
      }
    }
  }
}

// K4 (thin): out = elu(partial + cat(lrelu(rf),lrelu(rb)) @ fco_w[0:2CI,:])
// f-quad ownership: 32 vector weight loads/thread instead of 128 scalar.
__global__ __launch_bounds__(256, 2) void k_out(const void* __restrict__ xr,
                                                const void* __restrict__ fcowp,
                                                const float* __restrict__ R, void* dout){
  int blk = blockIdx.x, tid = threadIdx.x;
  int b = blk >> 5, i0 = (blk & 31) * 4;
  __shared__ __align__(16) float inl[4*2*CI];     // 4 rows x 128
  __shared__ __align__(16) float red4[4*64*20];   // partials, stride 20
  int mode = blk_mode(xr, 256, tid);
  for (int t = tid; t < 4*2*CI; t += 256){
    int r = t >> 7, k = t & 127;
    int row = b*N + i0 + r;
    inl[r*128 + k] = (k < CI) ? lrelu(R[O_RF + row*CI + k])
                              : lrelu(R[O_RB + row*CI + (k - CI)]);
  }
  __syncthreads();
  // thread=(cg,lq): cg owns 32 c's, lq owns l-quad
  {
    int cg = tid >> 6, lq = tid & 63;
    int c0 = cg * 32, l0 = lq * 4;
    float a4[4][4] = {{0,0,0,0},{0,0,0,0},{0,0,0,0},{0,0,0,0}};
    if (mode){
      const unsigned short* fu = (const unsigned short*)fcowp;
      #pragma unroll 4
      for (int c = c0; c < c0+32; ++c){
        uint2 wq = *(const uint2*)&fu[c*L1 + l0];
        float w0,w1,w2,w3; bf2x(wq.x,w0,w1); bf2x(wq.y,w2,w3);
        #pragma unroll
        for (int r = 0; r < 4; ++r){
          float xv = inl[r*128 + c];          // wave-uniform -> LDS broadcast
          a4[r][0] += xv*w0; a4[r][1] += xv*w1;
          a4[r][2] += xv*w2; a4[r][3] += xv*w3;
        }
      }
    } else {
      const float* ff = (const float*)fcowp;
      #pragma unroll 4
      for (int c = c0; c < c0+32; ++c){
        float4 w4 = *(const float4*)&ff[c*L1 + l0];
        #pragma unroll
        for (int r = 0; r < 4; ++r){
          float xv = inl[r*128 + c];
          a4[r][0] += xv*w4.x; a4[r][1] += xv*w4.y;
          a4[r][2] += xv*w4.z; a4[r][3] += xv*w4.w;
        }
      }
    }
    float* rp = &red4[(cg*64 + lq)*20];
    #pragma unroll
    for (int r = 0; r < 4; ++r)
      *(float4*)&rp[r*4] = *(const float4*)&a4[r][0];
  }
  __syncthreads();
  int l = tid;
  {
    int fq2 = l >> 2, j = l & 3;
    #pragma unroll
    for (int r = 0; r < 4; ++r){
      float s0 = red4[(0*64+fq2)*20 + r*4 + j];
      float s1 = red4[(1*64+fq2)*20 + r*4 + j];
      float s2 = red4[(2*64+fq2)*20 + r*4 + j];
      float s3 = red4[(3*64+fq2)*20 + r*4 + j];
      float acc = R[O_H1 + (b*N + i0 + r)*L1 + l] + (s0+s1)+(s2+s3);
      float o = acc > 0.f ? acc : expm1f(acc);
      int idx = (b*N + i0 + r)*L1 + l;
      if (mode) ((__hip_bfloat16*)dout)[idx] = __float2bfloat16(o);
      else      ((float*)dout)[idx] = o;
    }
  }
}

extern "C" void kernel_launch(void* const* d_in, const int* in_sizes, int n_in,
                              void* d_out, int out_size, void* d_ws, size_t ws_size,
                              hipStream_t stream){
  (void)in_sizes; (void)n_in; (void)out_size; (void)ws_size;
  float* ws = (float*)d_ws;
  AttArgs A;
  A.we = d_in[2]; A.x = d_in[0]; A.wfcw = d_in[5]; A.wfcb = d_in[6];
  A.fcw = d_in[7]; A.fcb = d_in[8]; A.fccb = d_in[10];
  A.wihf = d_in[11]; A.bihf = d_in[13]; A.bhhf = d_in[14];
  A.wihb = d_in[15]; A.bihb = d_in[17]; A.bhhb = d_in[18];
  hipLaunchKernelGGL(k_h_pq,   dim3(512),    dim3(256), 0, stream,
                     d_in[0], d_in[3], d_in[4], d_in[9], d_in[7], ws);
  hipLaunchKernelGGL(k_att,    dim3(B*N/2),  dim3(256), 0, stream, A, (const int*)d_in[1], ws);
  hipLaunchKernelGGL(k_rnn_h1, dim3(544),    dim3(256), 0, stream,
                     d_in[0], d_in[12], d_in[16], d_in[19], d_in[20], ws);
  hipLaunchKernelGGL(k_out,    dim3(512),    dim3(256), 0, stream,
                     d_in[0], d_in[19], ws, d_out);
}

// Round 8
// 182.274 us; speedup vs baseline: 1.0969x; 1.0320x over previous
//
#include <hip/hip_runtime.h>
#include <hip/hip_bf16.h>

#define DEV static __device__ __forceinline__

constexpr int B=16, N=128, FIN=128, FOUT=256, EOUT=64, BINW=14, BOUT=64, CI=64, L1=256;

// ---- scratch layout in d_ws (float offsets) ----
constexpr int O_H   = 0;                       // [B,N,FOUT]
constexpr int O_S   = O_H  + B*N*FOUT;         // [B,N]
constexpr int O_SU  = O_S  + B*N;
constexpr int O_SV  = O_SU + B*N;
constexpr int O_ATT = O_SV + B*N;              // [B,N,N]
constexpr int O_ZF  = O_ATT+ B*N*N;            // [B,N,CI]
constexpr int O_ZB  = O_ZF + B*N*CI;
constexpr int O_RF  = O_ZB + B*N*CI;
constexpr int O_RB  = O_RF + B*N*CI;
constexpr int O_H1  = O_RB + B*N*CI;           // [B,N,L1] : partial = h1@fco_w[2CI:,:] + fco_b

DEV float bf16_to_f32(unsigned short u){
  unsigned int x = ((unsigned int)u) << 16; float f;
  __builtin_memcpy(&f, &x, 4); return f;
}
DEV void bf2x(unsigned int u, float& lo, float& hi){
  unsigned int a = u << 16, b = u & 0xFFFF0000u;
  __builtin_memcpy(&lo, &a, 4); __builtin_memcpy(&hi, &b, 4);
}
DEV float lrelu(float x){ return x > 0.f ? x : 0.01f * x; }
DEV float bcastf(float v, int lane){
  return __builtin_bit_cast(float, __builtin_amdgcn_readlane(__builtin_bit_cast(int, v), lane));
}
DEV float ldf(const void* p, int i, int m){
  return m ? bf16_to_f32(((const unsigned short*)p)[i]) : ((const float*)p)[i];
}
// block-parallel dtype detect (bf16 ~100% of sampled exps in [100,140]; f32 ~58%)
DEV int blk_mode(const void* x, int nt, int tid){
  const unsigned short* u = (const unsigned short*)x;
  int e = (u[tid & 255] >> 7) & 0xFF;
  int cnt = __syncthreads_count(e >= 100 && e <= 140);
  return cnt * 4 >= nt * 3;
}

// K1: h = x@W ; s = h·fcc_w ; P,Q (LDS only) ; su/sv fused (sv[r]==sv[r+64])
// 512 blocks x 4 rows, 2 blocks/CU. Both GEMMs use quad-ownership:
//  x@W: thread=(cg4,fq): 32 vector loads/thread (was 128 scalar).
//  P/Q: thread=(cg16,oq): 32 vector loads/thread (was 256 scalar).
// Partials reduced via padded LDS (sbuf overlays both reductions).
__global__ __launch_bounds__(256, 2) void k_h_pq(const void* __restrict__ xr,
                                                 const void* __restrict__ Wp,
                                                 const void* __restrict__ Ap,
                                                 const void* __restrict__ fccwp,
                                                 const void* __restrict__ fcwp,
                                                 float* __restrict__ ws){
  int blk = blockIdx.x, tid = threadIdx.x;
  int b = blk >> 5, i0 = (blk & 31) * 4;
  __shared__ __align__(16) float xl[4*FIN];
  __shared__ __align__(16) float hrow[4*FOUT];
  __shared__ __align__(16) float pl[4*EOUT];
  __shared__ __align__(16) float ql[4*EOUT];
  __shared__ float red[16];
  __shared__ __align__(16) float sbuf[16*520];    // x@W partials (stride 20) / P,Q partials (stride 520)
  float* red4 = sbuf;
  int mode = blk_mode(xr, 256, tid);
  if (mode){
    const unsigned short* xu = (const unsigned short*)xr + (size_t)(b*N + i0)*FIN;
    for (int t = tid; t < 4*FIN/8; t += 256){
      uint4 u4 = ((const uint4*)xu)[t];
      float* o = &xl[t*8];
      bf2x(u4.x,o[0],o[1]); bf2x(u4.y,o[2],o[3]); bf2x(u4.z,o[4],o[5]); bf2x(u4.w,o[6],o[7]);
    }
  } else {
    const float* xf = (const float*)xr + (size_t)(b*N + i0)*FIN;
    for (int t4 = tid; t4 < 4*FIN/4; t4 += 256)
      *(float4*)&xl[t4*4] = ((const float4*)xf)[t4];
  }
  __syncthreads();
  // ---- h = x@W : f-quad ownership ----
  {
    int cg = tid >> 6, fq = tid & 63;
    int c0 = cg * 32, f0 = fq * 4;
    float a4[4][4] = {{0,0,0,0},{0,0,0,0},{0,0,0,0},{0,0,0,0}};
    if (mode){
      const unsigned short* Wu = (const unsigned short*)Wp;
      #pragma unroll 4
      for (int c = c0; c < c0+32; ++c){
        uint2 wq = *(const uint2*)&Wu[c*FOUT + f0];
        float w0,w1,w2,w3; bf2x(wq.x,w0,w1); bf2x(wq.y,w2,w3);
        #pragma unroll
        for (int r = 0; r < 4; ++r){
          float xv = xl[r*FIN + c];           // wave-uniform -> LDS broadcast
          a4[r][0] += xv*w0; a4[r][1] += xv*w1;
          a4[r][2] += xv*w2; a4[r][3] += xv*w3;
        }
      }
    } else {
      const float* Wf = (const float*)Wp;
      #pragma unroll 4
      for (int c = c0; c < c0+32; ++c){
        float4 w4 = *(const float4*)&Wf[c*FOUT + f0];
        #pragma unroll
        for (int r = 0; r < 4; ++r){
          float xv = xl[r*FIN + c];
          a4[r][0] += xv*w4.x; a4[r][1] += xv*w4.y;
          a4[r][2] += xv*w4.z; a4[r][3] += xv*w4.w;
        }
      }
    }
    float* rp = &red4[(cg*64 + fq)*20];
    #pragma unroll
    for (int r = 0; r < 4; ++r)
      *(float4*)&rp[r*4] = *(const float4*)&a4[r][0];
  }
  __syncthreads();
  int f = tid;
  float acc[4];
  {
    int fq2 = f >> 2, j = f & 3;
    #pragma unroll
    for (int r = 0; r < 4; ++r){
      float s0 = red4[(0*64+fq2)*20 + r*4 + j];
      float s1 = red4[(1*64+fq2)*20 + r*4 + j];
      float s2 = red4[(2*64+fq2)*20 + r*4 + j];
      float s3 = red4[(3*64+fq2)*20 + r*4 + j];
      acc[r] = (s0+s1)+(s2+s3);
    }
  }
  float fw = ldf(fccwp, f, mode);
  #pragma unroll
  for (int r = 0; r < 4; ++r){
    ws[O_H + (b*N + i0 + r)*FOUT + f] = acc[r];
    hrow[r*FOUT + f] = acc[r];
  }
  #pragma unroll
  for (int r = 0; r < 4; ++r){
    float v = acc[r] * fw;
    for (int off = 32; off; off >>= 1) v += __shfl_down(v, off);
    if ((tid & 63) == 0) red[(tid >> 6)*4 + r] = v;
  }
  __syncthreads();   // also separates red4 reads from sbuf re-use below
  if (tid < 4){
    float s = red[tid] + red[4+tid] + red[8+tid] + red[12+tid];
    ws[O_S + b*N + i0 + tid] = s;
  }
  // ---- P/Q GEMM : o-quad ownership (cg16 owns 16 c's, oq owns o-quad) ----
  {
    int cg = tid >> 4, oq = tid & 15;
    int c0 = cg * 16, o0 = oq * 4;
    float pa[4][4] = {{0,0,0,0},{0,0,0,0},{0,0,0,0},{0,0,0,0}};
    float qa[4][4] = {{0,0,0,0},{0,0,0,0},{0,0,0,0},{0,0,0,0}};
    if (mode){
      const unsigned short* Au = (const unsigned short*)Ap;
      #pragma unroll
      for (int cc = 0; cc < 16; cc += 4){
        float ha[4][4];
        #pragma unroll
        for (int r = 0; r < 4; ++r)
          *(float4*)&ha[r][0] = *(const float4*)&hrow[r*FOUT + c0 + cc];
        #pragma unroll
        for (int j = 0; j < 4; ++j){
          int c = c0 + cc + j;
          uint2 wp = *(const uint2*)&Au[c*EOUT + o0];
          uint2 wq2 = *(const uint2*)&Au[(FOUT + c)*EOUT + o0];
          float p0,p1,p2,p3,q0,q1,q2,q3;
          bf2x(wp.x,p0,p1);  bf2x(wp.y,p2,p3);
          bf2x(wq2.x,q0,q1); bf2x(wq2.y,q2,q3);
          #pragma unroll
          for (int r = 0; r < 4; ++r){
            float xv = ha[r][j];
            pa[r][0] += xv*p0; pa[r][1] += xv*p1; pa[r][2] += xv*p2; pa[r][3] += xv*p3;
            qa[r][0] += xv*q0; qa[r][1] += xv*q1; qa[r][2] += xv*q2; qa[r][3] += xv*q3;
          }
        }
      }
    } else {
      const float* Af = (const float*)Ap;
      #pragma unroll
      for (int cc = 0; cc < 16; cc += 4){
        float ha[4][4];
        #pragma unroll
        for (int r = 0; r < 4; ++r)
          *(float4*)&ha[r][0] = *(const float4*)&hrow[r*FOUT + c0 + cc];
        #pragma unroll
        for (int j = 0; j < 4; ++j){
          int c = c0 + cc + j;
          float4 wp4 = *(const float4*)&Af[c*EOUT + o0];
          float4 wq4 = *(const float4*)&Af[(FOUT + c)*EOUT + o0];
          #pragma unroll
          for (int r = 0; r < 4; ++r){
            float xv = ha[r][j];
            pa[r][0] += xv*wp4.x; pa[r][1] += xv*wp4.y;
            pa[r][2] += xv*wp4.z; pa[r][3] += xv*wp4.w;
            qa[r][0] += xv*wq4.x; qa[r][1] += xv*wq4.y;
            qa[r][2] += xv*wq4.z; qa[r][3] += xv*wq4.w;
          }
        }
      }
    }
    float* rp = sbuf + cg*520;    // out = (pq*4 + r)*64 + o ; 16 partials per out
    #pragma unroll
    for (int r = 0; r < 4; ++r){
      *(float4*)&rp[r*64 + o0]       = *(const float4*)&pa[r][0];
      *(float4*)&rp[256 + r*64 + o0] = *(const float4*)&qa[r][0];
    }
  }
  __syncthreads();
  {
    float s0 = 0.f, s1 = 0.f;
    #pragma unroll
    for (int cg2 = 0; cg2 < 16; ++cg2){
      s0 += sbuf[cg2*520 + tid];          // lane-contiguous -> conflict-free
      s1 += sbuf[cg2*520 + 256 + tid];
    }
    pl[tid] = s0;   // pl[row*64 + o], row = tid>>6
    ql[tid] = s1;
  }
  __syncthreads();
  // su for rows i0..i0+3 ; sv for pairs (value keyed by j2=(2r)&127; sv[r]==sv[r+64])
  {
    int o = tid & 63, w = tid >> 6;
    float fw2 = ldf(fcwp, o, mode);
    int w2 = (w < 2) ? w : 0;            // waves 2,3 compute a dummy s3 (not stored)
    float s1 = lrelu(pl[w*EOUT + o]        + ql[w*EOUT + o])        * fw2;
    float s3 = lrelu(pl[(2*w2)*EOUT + o]   + ql[(2*w2+1)*EOUT + o]) * fw2;
    for (int off = 32; off; off >>= 1){
      s1 += __shfl_down(s1, off); s3 += __shfl_down(s3, off);
    }
    if (o == 0){
      ws[O_SU + b*N + i0 + w] = s1;
      if (w < 2){
        int r1 = (i0 >> 1) + w;
        ws[O_SV + b*N + r1]      = s3;
        ws[O_SV + b*N + r1 + 64] = s3;
      }
    }
  }
}

struct AttArgs { const void *we,*x,*wfcw,*wfcb,*fcw,*fcb,*fccb,*wihf,*bihf,*bhhf,*wihb,*bihb,*bhhb; };

// K2: per block: TWO (b,i) rows. edge-MLP + mask + softmax -> att ; hn_pre ; z
__global__ __launch_bounds__(256) void k_att(AttArgs A, const int* __restrict__ adj,
                                             float* __restrict__ ws){
  int blk = blockIdx.x, tid = threadIdx.x;
  int half = tid >> 7, j = tid & 127, wv = (tid >> 6) & 1;
  int tau = blk*2 + half;
  int b = tau >> 7, i = tau & 127;
  __shared__ __align__(16) float wel[2][N*BINW];
  __shared__ __align__(16) float hnp[2][N];
  __shared__ __align__(16) float wfcwl[BINW*BOUT];
  __shared__ __align__(16) float wfcbl[BOUT];
  __shared__ __align__(16) float fcw2l[BOUT];
  __shared__ float red2[2][2];
  int mode = blk_mode(A.x, 256, tid);
  for (int t = tid; t < BINW*BOUT; t += 256) wfcwl[t] = ldf(A.wfcw, t, mode);
  if (tid < BOUT){ wfcbl[tid] = ldf(A.wfcb, tid, mode); fcw2l[tid] = ldf(A.fcw, EOUT + tid, mode); }
  if (mode){
    const unsigned short* weu = (const unsigned short*)A.we + (size_t)(b*N + i)*N*BINW;
    for (int t = j; t < N*BINW/8; t += 128){
      uint4 q = ((const uint4*)weu)[t];
      float* o = &wel[half][t*8];
      bf2x(q.x,o[0],o[1]); bf2x(q.y,o[2],o[3]); bf2x(q.z,o[4],o[5]); bf2x(q.w,o[6],o[7]);
    }
  } else {
    const float* wef = (const float*)A.we + (size_t)(b*N + i)*N*BINW;
    for (int t4 = j; t4 < N*BINW/4; t4 += 128)
      *(float4*)&wel[half][t4*4] = ((const float4*)wef)[t4];
  }
  __syncthreads();
  float wr[BINW];
  #pragma unroll
  for (int t = 0; t < BINW; ++t) wr[t] = wel[half][j*BINW + t];
  float wcon = 0.f;
  for (int o = 0; o < BOUT; o += 4){
    float4 bb = *(const float4*)&wfcbl[o];
    float w0 = bb.x, w1 = bb.y, w2 = bb.z, w3 = bb.w;
    #pragma unroll
    for (int t = 0; t < BINW; ++t){
      float4 w4 = *(const float4*)&wfcwl[t*BOUT + o];
      w0 = fmaf(wr[t], w4.x, w0); w1 = fmaf(wr[t], w4.y, w1);
      w2 = fmaf(wr[t], w4.z, w2); w3 = fmaf(wr[t], w4.w, w3);
    }
    float4 f4 = *(const float4*)&fcw2l[o];
    wcon += lrelu(w0)*f4.x + lrelu(w1)*f4.y + lrelu(w2)*f4.z + lrelu(w3)*f4.w;
  }
  const float* R = ws;
  float econ = (i < 64) ? R[O_SU + b*N + 2*i + (j >= 64 ? 1 : 0)]
                        : R[O_SV + b*N + j];
  float etot = econ + wcon + ldf(A.fcb, 0, mode);
  float m = (adj[(b*N + i)*N + j] > 0) ? etot : -9e15f;
  float mx = m;
  for (int off = 32; off; off >>= 1) mx = fmaxf(mx, __shfl_xor(mx, off));
  if ((tid & 63) == 0) red2[half][wv] = mx;
  __syncthreads();
  mx = fmaxf(red2[half][0], red2[half][1]);
  float ev = expf(m - mx);
  float sum = ev;
  for (int off = 32; off; off >>= 1) sum += __shfl_xor(sum, off);
  __syncthreads();
  if ((tid & 63) == 0) red2[half][wv] = sum;
  __syncthreads();
  sum = red2[half][0] + red2[half][1];
  float att = ev / sum;
  ws[O_ATT + (b*N + i)*N + j] = att;
  float sbi = R[O_S + b*N + i];
  hnp[half][j] = lrelu(att * sbi + ldf(A.fccb, 0, mode));
  __syncthreads();
  // z[b,i,c] both directions (per half: 2 waves = 2 directions)
  {
    int d = wv, c = tid & 63;
    float acc = ldf(d ? A.bihb : A.bihf, c, mode) + ldf(d ? A.bhhb : A.bhhf, c, mode);
    const void* wihp = d ? A.wihb : A.wihf;
    if (mode){
      const uint4* wq = (const uint4*)((const unsigned short*)wihp + c*N);
      #pragma unroll 4
      for (int k = 0; k < N; k += 8){
        uint4 q = wq[k >> 3];
        float w0,w1,w2,w3,w4,w5,w6,w7;
        bf2x(q.x,w0,w1); bf2x(q.y,w2,w3); bf2x(q.z,w4,w5); bf2x(q.w,w6,w7);
        float4 h0 = *(const float4*)&hnp[half][k];
        float4 h1 = *(const float4*)&hnp[half][k+4];
        acc += h0.x*w0 + h0.y*w1 + h0.z*w2 + h0.w*w3
             + h1.x*w4 + h1.y*w5 + h1.z*w6 + h1.w*w7;
      }
    } else {
      const float* wf = (const float*)wihp + c*N;
      #pragma unroll 8
      for (int k = 0; k < N; k += 4){
        float4 h4 = *(const float4*)&hnp[half][k];
        float4 w4 = *(const float4*)&wf[k];
        acc += h4.x*w4.x + h4.y*w4.y + h4.z*w4.z + h4.w*w4.w;
      }
    }
    ws[(d ? O_ZB : O_ZF) + (b*N + i)*CI + c] = acc;
  }
}

// K3: blocks 0..31: serial RNN chains (wave 0).
//     blocks 32..543: h1 = att@h (4 rows) FUSED with partial = h1@fco_w[2CI:,:]+fco_b.
// Partial GEMM uses l-quad ownership: 64 vector loads/thread instead of 256 scalar.
__global__ __launch_bounds__(256, 1) void k_rnn_h1(const void* __restrict__ xr,
                                                   const void* __restrict__ whhf,
                                                   const void* __restrict__ whhb,
                                                   const void* __restrict__ fcowp,
                                                   const void* __restrict__ fcobp,
                                                   float* __restrict__ ws){
  __shared__ __align__(16) float sh[N*CI];   // rnn: 32 KB; h1: attT(512)+h1l(1024)+red4(5120)
  int blk = blockIdx.x, tid = threadIdx.x;
  int mode = blk_mode(xr, 256, tid);
  const float* R = ws;
  if (blk < 32){
    int d = blk >> 4, b = blk & 15;
    const int zb = (d ? O_ZB : O_ZF) + b*N*CI;
    const int ob = (d ? O_RB : O_RF) + b*N*CI;
    for (int it = tid; it < N*CI/4; it += 256)
      *(float4*)&sh[it*4] = *(const float4*)&ws[zb + it*4];
    __syncthreads();
    if (tid < 64){
      int c = tid;
      const void* whhp = d ? whhb : whhf;
      float wreg[CI];
      if (mode){
        const uint4* wq = (const uint4*)((const unsigned short*)whhp + c*CI);
        #pragma unroll
        for (int k = 0; k < CI; k += 8){
          uint4 q = wq[k >> 3];
          bf2x(q.x,wreg[k+0],wreg[k+1]); bf2x(q.y,wreg[k+2],wreg[k+3]);
          bf2x(q.z,wreg[k+4],wreg[k+5]); bf2x(q.w,wreg[k+6],wreg[k+7]);
        }
      } else {
        const float* wf = (const float*)whhp + c*CI;
        #pragma unroll
        for (int k = 0; k < CI; k += 4){
          float4 w4 = *(const float4*)&wf[k];
          wreg[k]=w4.x; wreg[k+1]=w4.y; wreg[k+2]=w4.z; wreg[k+3]=w4.w;
        }
      }
      const int step = d ? -1 : 1;
      int tt = d ? (N-1) : 0;
      float hv = 0.f;
      float z = sh[tt*CI + c];    // single wave: DS ops in-order, no barrier needed
      for (int t = 0; t < N; ++t){
        int ti = tt + step; ti = ti < 0 ? 0 : (ti > N-1 ? N-1 : ti);
        float znext = sh[ti*CI + c];
        float s[CI];
        #pragma unroll
        for (int k = 0; k < CI; ++k) s[k] = bcastf(hv, k);   // batched readlanes
#if __has_builtin(__builtin_amdgcn_sched_barrier)
        __builtin_amdgcn_sched_barrier(0);
#endif
        float a0 = z, a1 = 0.f, a2 = 0.f, a3 = 0.f;
        #pragma unroll
        for (int k = 0; k < CI; k += 4){
          a0 = fmaf(s[k+0], wreg[k+0], a0);
          a1 = fmaf(s[k+1], wreg[k+1], a1);
          a2 = fmaf(s[k+2], wreg[k+2], a2);
          a3 = fmaf(s[k+3], wreg[k+3], a3);
        }
        float x = (a0+a1)+(a2+a3);
        x = fminf(15.f, fmaxf(-15.f, x));
        float p = __expf(2.f * x);
        hv = (p - 1.f) * __builtin_amdgcn_rcpf(p + 1.f);
        sh[tt*CI + c] = hv;
        z = znext;
        tt += step;
      }
    }
    __syncthreads();
    for (int it = tid; it < N*CI/4; it += 256)
      *(float4*)&ws[ob + it*4] = *(const float4*)&sh[it*4];
  } else {
    int task = blk - 32;                 // 0..511, 4 rows each
    int b = task >> 5, i0 = (task & 31) * 4;
    int f = tid;
    float* attT = sh;                    // 512
    float* h1l  = sh + 512;              // 1024
    float* red4 = sh + 1536;             // 4*64*20 = 5120
    for (int t = tid; t < 4*N; t += 256){
      int r = t >> 7, k = t & 127;
      attT[k*4 + r] = R[O_ATT + (b*N + i0 + r)*N + k];
    }
    __syncthreads();
    float acc[4] = {0,0,0,0};
    #pragma unroll 4
    for (int k = 0; k < N; ++k){
      float hv = R[O_H + (b*N + k)*FOUT + f];
      float4 a0 = *(const float4*)&attT[k*4];
      acc[0] += a0.x*hv; acc[1] += a0.y*hv; acc[2] += a0.z*hv; acc[3] += a0.w*hv;
    }
    #pragma unroll
    for (int r = 0; r < 4; ++r) h1l[r*FOUT + f] = acc[r];
    __syncthreads();
    // partial = h1 @ fco_w[2CI:,:] : l-quad ownership (64 vector loads/thread)
    {
      int cg = tid >> 6, lq = tid & 63;
      int c0 = cg * 64, l0 = lq * 4;
      float p44[4][4] = {{0,0,0,0},{0,0,0,0},{0,0,0,0},{0,0,0,0}};
      if (mode){
        const unsigned short* fu = (const unsigned short*)fcowp + (size_t)(2*CI)*L1;
        #pragma unroll 4
        for (int c = c0; c < c0+64; ++c){
          uint2 wq = *(const uint2*)&fu[c*L1 + l0];
          float w0,w1,w2,w3; bf2x(wq.x,w0,w1); bf2x(wq.y,w2,w3);
          #pragma unroll
          for (int r = 0; r < 4; ++r){
            float hv = h1l[r*FOUT + c];        // wave-uniform -> LDS broadcast
            p44[r][0] += hv*w0; p44[r][1] += hv*w1;
            p44[r][2] += hv*w2; p44[r][3] += hv*w3;
          }
        }
      } else {
        const float* ff = (const float*)fcowp + (size_t)(2*CI)*L1;
        #pragma unroll 4
        for (int c = c0; c < c0+64; ++c){
          float4 w4 = *(const float4*)&ff[c*L1 + l0];
          #pragma unroll
          for (int r = 0; r < 4; ++r){
            float hv = h1l[r*FOUT + c];
            p44[r][0] += hv*w4.x; p44[r][1] += hv*w4.y;
            p44[r][2] += hv*w4.z; p44[r][3] += hv*w4.w;
          }
        }
      }
      float* rp = &red4[(cg*64 + lq)*20];
      #pragma unroll
      for (int r = 0; r < 4; ++r)
        *(float4*)&rp[r*4] = *(const float4*)&p44[r][0];
    }
    __syncthreads();
    {
      int fq2 = f >> 2, j = f & 3;
      float bias = ldf(fcobp, f, mode);
      #pragma unroll
      for (int r = 0; r < 4; ++r){
        float s0 = red4[(0*64+fq2)*20 + r*4 + j];
        float s1 = red4[(1*64+fq2)*20 + r*4 + j];
        float s2 = red4[(2*64+fq2)*20 + r*4 + j];
        float s3 = red4[(3*64+fq2)*20 + r*4 + j];
        ws[O_H1 + (b*N + i0 + r)*L1 + f] = bias + (s0+s1)+(s2+s3);
      }
    }
  }
}

// K4 (thin): out = elu(partial + cat(lrelu(rf),lrelu(rb)) @ fco_w[0:2CI,:])
// f-quad ownership: 32 vector weight loads/thread instead of 128 scalar.
__global__ __launch_bounds__(256, 2) void k_out(const void* __restrict__ xr,
                                                const void* __restrict__ fcowp,
                                                const float* __restrict__ R, void* dout){
  int blk = blockIdx.x, tid = threadIdx.x;
  int b = blk >> 5, i0 = (blk & 31) * 4;
  __shared__ __align__(16) float inl[4*2*CI];     // 4 rows x 128
  __shared__ __align__(16) float red4[4*64*20];   // partials, stride 20
  int mode = blk_mode(xr, 256, tid);
  for (int t = tid; t < 4*2*CI; t += 256){
    int r = t >> 7, k = t & 127;
    int row = b*N + i0 + r;
    inl[r*128 + k] = (k < CI) ? lrelu(R[O_RF + row*CI + k])
                              : lrelu(R[O_RB + row*CI + (k - CI)]);
  }
  __syncthreads();
  // thread=(cg,lq): cg owns 32 c's, lq owns l-quad
  {
    int cg = tid >> 6, lq = tid & 63;
    int c0 = cg * 32, l0 = lq * 4;
    float a4[4][4] = {{0,0,0,0},{0,0,0,0},{0,0,0,0},{0,0,0,0}};
    if (mode){
      const unsigned short* fu = (const unsigned short*)fcowp;
      #pragma unroll 4
      for (int c = c0; c < c0+32; ++c){
        uint2 wq = *(const uint2*)&fu[c*L1 + l0];
        float w0,w1,w2,w3; bf2x(wq.x,w0,w1); bf2x(wq.y,w2,w3);
        #pragma unroll
        for (int r = 0; r < 4; ++r){
          float xv = inl[r*128 + c];          // wave-uniform -> LDS broadcast
          a4[r][0] += xv*w0; a4[r][1] += xv*w1;
          a4[r][2] += xv*w2; a4[r][3] += xv*w3;
        }
      }
    } else {
      const float* ff = (const float*)fcowp;
      #pragma unroll 4
      for (int c = c0; c < c0+32; ++c){
        float4 w4 = *(const float4*)&ff[c*L1 + l0];
        #pragma unroll
        for (int r = 0; r < 4; ++r){
          float xv = inl[r*128 + c];
          a4[r][0] += xv*w4.x; a4[r][1] += xv*w4.y;
          a4[r][2] += xv*w4.z; a4[r][3] += xv*w4.w;
        }
      }
    }
    float* rp = &red4[(cg*64 + lq)*20];
    #pragma unroll
    for (int r = 0; r < 4; ++r)
      *(float4*)&rp[r*4] = *(const float4*)&a4[r][0];
  }
  __syncthreads();
  int l = tid;
  {
    int fq2 = l >> 2, j = l & 3;
    #pragma unroll
    for (int r = 0; r < 4; ++r){
      float s0 = red4[(0*64+fq2)*20 + r*4 + j];
      float s1 = red4[(1*64+fq2)*20 + r*4 + j];
      float s2 = red4[(2*64+fq2)*20 + r*4 + j];
      float s3 = red4[(3*64+fq2)*20 + r*4 + j];
      float acc = R[O_H1 + (b*N + i0 + r)*L1 + l] + (s0+s1)+(s2+s3);
      float o = acc > 0.f ? acc : expm1f(acc);
      int idx = (b*N + i0 + r)*L1 + l;
      if (mode) ((__hip_bfloat16*)dout)[idx] = __float2bfloat16(o);
      else      ((float*)dout)[idx] = o;
    }
  }
}

extern "C" void kernel_launch(void* const* d_in, const int* in_sizes, int n_in,
                              void* d_out, int out_size, void* d_ws, size_t ws_size,
                              hipStream_t stream){
  (void)in_sizes; (void)n_in; (void)out_size; (void)ws_size;
  float* ws = (float*)d_ws;
  AttArgs A;
  A.we = d_in[2]; A.x = d_in[0]; A.wfcw = d_in[5]; A.wfcb = d_in[6];
  A.fcw = d_in[7]; A.fcb = d_in[8]; A.fccb = d_in[10];
  A.wihf = d_in[11]; A.bihf = d_in[13]; A.bhhf = d_in[14];
  A.wihb = d_in[15]; A.bihb = d_in[17]; A.bhhb = d_in[18];
  hipLaunchKernelGGL(k_h_pq,   dim3(512),    dim3(256), 0, stream,
                     d_in[0], d_in[3], d_in[4], d_in[9], d_in[7], ws);
  hipLaunchKernelGGL(k_att,    dim3(B*N/2),  dim3(256), 0, stream, A, (const int*)d_in[1], ws);
  hipLaunchKernelGGL(k_rnn_h1, dim3(544),    dim3(256), 0, stream,
                     d_in[0], d_in[12], d_in[16], d_in[19], d_in[20], ws);
  hipLaunchKernelGGL(k_out,    dim3(512),    dim3(256), 0, stream,
                     d_in[0], d_in[19], ws, d_out);
}

// Round 9
// 180.374 us; speedup vs baseline: 1.1085x; 1.0105x over previous
//
#include <hip/hip_runtime.h>
#include <hip/hip_bf16.h>

#define DEV static __device__ __forceinline__

constexpr int B=16, N=128, FIN=128, FOUT=256, EOUT=64, BINW=14, BOUT=64, CI=64, L1=256;

// ---- scratch layout in d_ws (float offsets) ----
constexpr int O_H   = 0;                       // [B,N,FOUT]
constexpr int O_S   = O_H  + B*N*FOUT;         // [B,N]
constexpr int O_SU  = O_S  + B*N;
constexpr int O_SV  = O_SU + B*N;
constexpr int O_ATT = O_SV + B*N;              // [B,N,N]
constexpr int O_ZF  = O_ATT+ B*N*N;            // [B,N,CI]
constexpr int O_ZB  = O_ZF + B*N*CI;
constexpr int O_RF  = O_ZB + B*N*CI;
constexpr int O_RB  = O_RF + B*N*CI;
constexpr int O_H1  = O_RB + B*N*CI;           // [B,N,L1] : partial = h1@fco_w[2CI:,:] + fco_b

DEV float bf16_to_f32(unsigned short u){
  unsigned int x = ((unsigned int)u) << 16; float f;
  __builtin_memcpy(&f, &x, 4); return f;
}
DEV void bf2x(unsigned int u, float& lo, float& hi){
  unsigned int a = u << 16, b = u & 0xFFFF0000u;
  __builtin_memcpy(&lo, &a, 4); __builtin_memcpy(&hi, &b, 4);
}
DEV float lrelu(float x){ return x > 0.f ? x : 0.01f * x; }
DEV float bcastf(float v, int lane){
  return __builtin_bit_cast(float, __builtin_amdgcn_readlane(__builtin_bit_cast(int, v), lane));
}
DEV float ldf(const void* p, int i, int m){
  return m ? bf16_to_f32(((const unsigned short*)p)[i]) : ((const float*)p)[i];
}
// block-parallel dtype detect (bf16 ~100% of sampled exps in [100,140]; f32 ~58%)
DEV int blk_mode(const void* x, int nt, int tid){
  const unsigned short* u = (const unsigned short*)x;
  int e = (u[tid & 255] >> 7) & 0xFF;
  int cnt = __syncthreads_count(e >= 100 && e <= 140);
  return cnt * 4 >= nt * 3;
}

// K1: h = x@W ; s = h·fcc_w ; P,Q (LDS only) ; su/sv fused (sv[r]==sv[r+64])
// 512 blocks x 4 rows, 2 blocks/CU. Both GEMMs use quad-ownership:
//  x@W: thread=(cg4,fq): 32 vector loads/thread (was 128 scalar).
//  P/Q: thread=(cg16,oq): 32 vector loads/thread (was 256 scalar).
// Partials reduced via padded LDS (sbuf overlays both reductions).
__global__ __launch_bounds__(256, 2) void k_h_pq(const void* __restrict__ xr,
                                                 const void* __restrict__ Wp,
                                                 const void* __restrict__ Ap,
                                                 const void* __restrict__ fccwp,
                                                 const void* __restrict__ fcwp,
                                                 float* __restrict__ ws){
  int blk = blockIdx.x, tid = threadIdx.x;
  int b = blk >> 5, i0 = (blk & 31) * 4;
  __shared__ __align__(16) float xl[4*FIN];
  __shared__ __align__(16) float hrow[4*FOUT];
  __shared__ __align__(16) float pl[4*EOUT];
  __shared__ __align__(16) float ql[4*EOUT];
  __shared__ float red[16];
  __shared__ __align__(16) float sbuf[16*520];    // x@W partials (stride 20) / P,Q partials (stride 520)
  float* red4 = sbuf;
  int mode = blk_mode(xr, 256, tid);
  if (mode){
    const unsigned short* xu = (const unsigned short*)xr + (size_t)(b*N + i0)*FIN;
    for (int t = tid; t < 4*FIN/8; t += 256){
      uint4 u4 = ((const uint4*)xu)[t];
      float* o = &xl[t*8];
      bf2x(u4.x,o[0],o[1]); bf2x(u4.y,o[2],o[3]); bf2x(u4.z,o[4],o[5]); bf2x(u4.w,o[6],o[7]);
    }
  } else {
    const float* xf = (const float*)xr + (size_t)(b*N + i0)*FIN;
    for (int t4 = tid; t4 < 4*FIN/4; t4 += 256)
      *(float4*)&xl[t4*4] = ((const float4*)xf)[t4];
  }
  __syncthreads();
  // ---- h = x@W : f-quad ownership ----
  {
    int cg = tid >> 6, fq = tid & 63;
    int c0 = cg * 32, f0 = fq * 4;
    float a4[4][4] = {{0,0,0,0},{0,0,0,0},{0,0,0,0},{0,0,0,0}};
    if (mode){
      const unsigned short* Wu = (const unsigned short*)Wp;
      #pragma unroll 4
      for (int c = c0; c < c0+32; ++c){
        uint2 wq = *(const uint2*)&Wu[c*FOUT + f0];
        float w0,w1,w2,w3; bf2x(wq.x,w0,w1); bf2x(wq.y,w2,w3);
        #pragma unroll
        for (int r = 0; r < 4; ++r){
          float xv = xl[r*FIN + c];           // wave-uniform -> LDS broadcast
          a4[r][0] += xv*w0; a4[r][1] += xv*w1;
          a4[r][2] += xv*w2; a4[r][3] += xv*w3;
        }
      }
    } else {
      const float* Wf = (const float*)Wp;
      #pragma unroll 4
      for (int c = c0; c < c0+32; ++c){
        float4 w4 = *(const float4*)&Wf[c*FOUT + f0];
        #pragma unroll
        for (int r = 0; r < 4; ++r){
          float xv = xl[r*FIN + c];
          a4[r][0] += xv*w4.x; a4[r][1] += xv*w4.y;
          a4[r][2] += xv*w4.z; a4[r][3] += xv*w4.w;
        }
      }
    }
    float* rp = &red4[(cg*64 + fq)*20];
    #pragma unroll
    for (int r = 0; r < 4; ++r)
      *(float4*)&rp[r*4] = *(const float4*)&a4[r][0];
  }
  __syncthreads();
  int f = tid;
  float acc[4];
  {
    int fq2 = f >> 2, j = f & 3;
    #pragma unroll
    for (int r = 0; r < 4; ++r){
      float s0 = red4[(0*64+fq2)*20 + r*4 + j];
      float s1 = red4[(1*64+fq2)*20 + r*4 + j];
      float s2 = red4[(2*64+fq2)*20 + r*4 + j];
      float s3 = red4[(3*64+fq2)*20 + r*4 + j];
      acc[r] = (s0+s1)+(s2+s3);
    }
  }
  float fw = ldf(fccwp, f, mode);
  #pragma unroll
  for (int r = 0; r < 4; ++r){
    ws[O_H + (b*N + i0 + r)*FOUT + f] = acc[r];
    hrow[r*FOUT + f] = acc[r];
  }
  #pragma unroll
  for (int r = 0; r < 4; ++r){
    float v = acc[r] * fw;
    for (int off = 32; off; off >>= 1) v += __shfl_down(v, off);
    if ((tid & 63) == 0) red[(tid >> 6)*4 + r] = v;
  }
  __syncthreads();   // also separates red4 reads from sbuf re-use below
  if (tid < 4){
    float s = red[tid] + red[4+tid] + red[8+tid] + red[12+tid];
    ws[O_S + b*N + i0 + tid] = s;
  }
  // ---- P/Q GEMM : o-quad ownership (cg16 owns 16 c's, oq owns o-quad) ----
  {
    int cg = tid >> 4, oq = tid & 15;
    int c0 = cg * 16, o0 = oq * 4;
    float pa[4][4] = {{0,0,0,0},{0,0,0,0},{0,0,0,0},{0,0,0,0}};
    float qa[4][4] = {{0,0,0,0},{0,0,0,0},{0,0,0,0},{0,0,0,0}};
    if (mode){
      const unsigned short* Au = (const unsigned short*)Ap;
      #pragma unroll
      for (int cc = 0; cc < 16; cc += 4){
        float ha[4][4];
        #pragma unroll
        for (int r = 0; r < 4; ++r)
          *(float4*)&ha[r][0] = *(const float4*)&hrow[r*FOUT + c0 + cc];
        #pragma unroll
        for (int j = 0; j < 4; ++j){
          int c = c0 + cc + j;
          uint2 wp = *(const uint2*)&Au[c*EOUT + o0];
          uint2 wq2 = *(const uint2*)&Au[(FOUT + c)*EOUT + o0];
          float p0,p1,p2,p3,q0,q1,q2,q3;
          bf2x(wp.x,p0,p1);  bf2x(wp.y,p2,p3);
          bf2x(wq2.x,q0,q1); bf2x(wq2.y,q2,q3);
          #pragma unroll
          for (int r = 0; r < 4; ++r){
            float xv = ha[r][j];
            pa[r][0] += xv*p0; pa[r][1] += xv*p1; pa[r][2] += xv*p2; pa[r][3] += xv*p3;
            qa[r][0] += xv*q0; qa[r][1] += xv*q1; qa[r][2] += xv*q2; qa[r][3] += xv*q3;
          }
        }
      }
    } else {
      const float* Af = (const float*)Ap;
      #pragma unroll
      for (int cc = 0; cc < 16; cc += 4){
        float ha[4][4];
        #pragma unroll
        for (int r = 0; r < 4; ++r)
          *(float4*)&ha[r][0] = *(const float4*)&hrow[r*FOUT + c0 + cc];
        #pragma unroll
        for (int j = 0; j < 4; ++j){
          int c = c0 + cc + j;
          float4 wp4 = *(const float4*)&Af[c*EOUT + o0];
          float4 wq4 = *(const float4*)&Af[(FOUT + c)*EOUT + o0];
          #pragma unroll
          for (int r = 0; r < 4; ++r){
            float xv = ha[r][j];
            pa[r][0] += xv*wp4.x; pa[r][1] += xv*wp4.y;
            pa[r][2] += xv*wp4.z; pa[r][3] += xv*wp4.w;
            qa[r][0] += xv*wq4.x; qa[r][1] += xv*wq4.y;
            qa[r][2] += xv*wq4.z; qa[r][3] += xv*wq4.w;
          }
        }
      }
    }
    float* rp = sbuf + cg*520;    // out = (pq*4 + r)*64 + o ; 16 partials per out
    #pragma unroll
    for (int r = 0; r < 4; ++r){
      *(float4*)&rp[r*64 + o0]       = *(const float4*)&pa[r][0];
      *(float4*)&rp[256 + r*64 + o0] = *(const float4*)&qa[r][0];
    }
  }
  __syncthreads();
  {
    float s0 = 0.f, s1 = 0.f;
    #pragma unroll
    for (int cg2 = 0; cg2 < 16; ++cg2){
      s0 += sbuf[cg2*520 + tid];          // lane-contiguous -> conflict-free
      s1 += sbuf[cg2*520 + 256 + tid];
    }
    pl[tid] = s0;   // pl[row*64 + o], row = tid>>6
    ql[tid] = s1;
  }
  __syncthreads();
  // su for rows i0..i0+3 ; sv for pairs (value keyed by j2=(2r)&127; sv[r]==sv[r+64])
  {
    int o = tid & 63, w = tid >> 6;
    float fw2 = ldf(fcwp, o, mode);
    int w2 = (w < 2) ? w : 0;            // waves 2,3 compute a dummy s3 (not stored)
    float s1 = lrelu(pl[w*EOUT + o]        + ql[w*EOUT + o])        * fw2;
    float s3 = lrelu(pl[(2*w2)*EOUT + o]   + ql[(2*w2+1)*EOUT + o]) * fw2;
    for (int off = 32; off; off >>= 1){
      s1 += __shfl_down(s1, off); s3 += __shfl_down(s3, off);
    }
    if (o == 0){
      ws[O_SU + b*N + i0 + w] = s1;
      if (w < 2){
        int r1 = (i0 >> 1) + w;
        ws[O_SV + b*N + r1]      = s3;
        ws[O_SV + b*N + r1 + 64] = s3;
      }
    }
  }
}

struct AttArgs { const void *we,*x,*wfcw,*wfcb,*fcw,*fcb,*fccb,*wihf,*bihf,*bhhf,*wihb,*bihb,*bhhb; };

// K2: per block: TWO (b,i) rows. edge-MLP + mask + softmax -> att ; hn_pre ; z
__global__ __launch_bounds__(256) void k_att(AttArgs A, const int* __restrict__ adj,
                                             float* __restrict__ ws){
  int blk = blockIdx.x, tid = threadIdx.x;
  int half = tid >> 7, j = tid & 127, wv = (tid >> 6) & 1;
  int tau = blk*2 + half;
  int b = tau >> 7, i = tau & 127;
  __shared__ __align__(16) float wel[2][N*BINW];
  __shared__ __align__(16) float hnp[2][N];
  __shared__ __align__(16) float wfcwl[BINW*BOUT];
  __shared__ __align__(16) float wfcbl[BOUT];
  __shared__ __align__(16) float fcw2l[BOUT];
  __shared__ float red2[2][2];
  int mode = blk_mode(A.x, 256, tid);
  for (int t = tid; t < BINW*BOUT; t += 256) wfcwl[t] = ldf(A.wfcw, t, mode);
  if (tid < BOUT){ wfcbl[tid] = ldf(A.wfcb, tid, mode); fcw2l[tid] = ldf(A.fcw, EOUT + tid, mode); }
  if (mode){
    const unsigned short* weu = (const unsigned short*)A.we + (size_t)(b*N + i)*N*BINW;
    for (int t = j; t < N*BINW/8; t += 128){
      uint4 q = ((const uint4*)weu)[t];
      float* o = &wel[half][t*8];
      bf2x(q.x,o[0],o[1]); bf2x(q.y,o[2],o[3]); bf2x(q.z,o[4],o[5]); bf2x(q.w,o[6],o[7]);
    }
  } else {
    const float* wef = (const float*)A.we + (size_t)(b*N + i)*N*BINW;
    for (int t4 = j; t4 < N*BINW/4; t4 += 128)
      *(float4*)&wel[half][t4*4] = ((const float4*)wef)[t4];
  }
  __syncthreads();
  float wr[BINW];
  #pragma unroll
  for (int t = 0; t < BINW; ++t) wr[t] = wel[half][j*BINW + t];
  float wcon = 0.f;
  for (int o = 0; o < BOUT; o += 4){
    float4 bb = *(const float4*)&wfcbl[o];
    float w0 = bb.x, w1 = bb.y, w2 = bb.z, w3 = bb.w;
    #pragma unroll
    for (int t = 0; t < BINW; ++t){
      float4 w4 = *(const float4*)&wfcwl[t*BOUT + o];
      w0 = fmaf(wr[t], w4.x, w0); w1 = fmaf(wr[t], w4.y, w1);
      w2 = fmaf(wr[t], w4.z, w2); w3 = fmaf(wr[t], w4.w, w3);
    }
    float4 f4 = *(const float4*)&fcw2l[o];
    wcon += lrelu(w0)*f4.x + lrelu(w1)*f4.y + lrelu(w2)*f4.z + lrelu(w3)*f4.w;
  }
  const float* R = ws;
  float econ = (i < 64) ? R[O_SU + b*N + 2*i + (j >= 64 ? 1 : 0)]
                        : R[O_SV + b*N + j];
  float etot = econ + wcon + ldf(A.fcb, 0, mode);
  float m = (adj[(b*N + i)*N + j] > 0) ? etot : -9e15f;
  float mx = m;
  for (int off = 32; off; off >>= 1) mx = fmaxf(mx, __shfl_xor(mx, off));
  if ((tid & 63) == 0) red2[half][wv] = mx;
  __syncthreads();
  mx = fmaxf(red2[half][0], red2[half][1]);
  float ev = expf(m - mx);
  float sum = ev;
  for (int off = 32; off; off >>= 1) sum += __shfl_xor(sum, off);
  __syncthreads();
  if ((tid & 63) == 0) red2[half][wv] = sum;
  __syncthreads();
  sum = red2[half][0] + red2[half][1];
  float att = ev / sum;
  ws[O_ATT + (b*N + i)*N + j] = att;
  float sbi = R[O_S + b*N + i];
  hnp[half][j] = lrelu(att * sbi + ldf(A.fccb, 0, mode));
  __syncthreads();
  // z[b,i,c] both directions (per half: 2 waves = 2 directions)
  {
    int d = wv, c = tid & 63;
    float acc = ldf(d ? A.bihb : A.bihf, c, mode) + ldf(d ? A.bhhb : A.bhhf, c, mode);
    const void* wihp = d ? A.wihb : A.wihf;
    if (mode){
      const uint4* wq = (const uint4*)((const unsigned short*)wihp + c*N);
      #pragma unroll 4
      for (int k = 0; k < N; k += 8){
        uint4 q = wq[k >> 3];
        float w0,w1,w2,w3,w4,w5,w6,w7;
        bf2x(q.x,w0,w1); bf2x(q.y,w2,w3); bf2x(q.z,w4,w5); bf2x(q.w,w6,w7);
        float4 h0 = *(const float4*)&hnp[half][k];
        float4 h1 = *(const float4*)&hnp[half][k+4];
        acc += h0.x*w0 + h0.y*w1 + h0.z*w2 + h0.w*w3
             + h1.x*w4 + h1.y*w5 + h1.z*w6 + h1.w*w7;
      }
    } else {
      const float* wf = (const float*)wihp + c*N;
      #pragma unroll 8
      for (int k = 0; k < N; k += 4){
        float4 h4 = *(const float4*)&hnp[half][k];
        float4 w4 = *(const float4*)&wf[k];
        acc += h4.x*w4.x + h4.y*w4.y + h4.z*w4.z + h4.w*w4.w;
      }
    }
    ws[(d ? O_ZB : O_ZF) + (b*N + i)*CI + c] = acc;
  }
}

// K3: blocks 0..31: serial RNN chains (wave 0).
//     blocks 32..543: h1 = att@h (4 rows, quad-ownership) FUSED with
//     partial = h1@fco_w[2CI:,:]+fco_b (l-quad). XCD-contiguous task swizzle
//     so each XCD's L2 holds only 2 batches' H panels.
__global__ __launch_bounds__(256, 1) void k_rnn_h1(const void* __restrict__ xr,
                                                   const void* __restrict__ whhf,
                                                   const void* __restrict__ whhb,
                                                   const void* __restrict__ fcowp,
                                                   const void* __restrict__ fcobp,
                                                   float* __restrict__ ws){
  __shared__ __align__(16) float sh[N*CI];   // rnn: 32 KB; h1: attT(512)+h1l(1024)+red4(5120)
  int blk = blockIdx.x, tid = threadIdx.x;
  int mode = blk_mode(xr, 256, tid);
  const float* R = ws;
  if (blk < 32){
    int d = blk >> 4, b = blk & 15;
    const int zb = (d ? O_ZB : O_ZF) + b*N*CI;
    const int ob = (d ? O_RB : O_RF) + b*N*CI;
    for (int it = tid; it < N*CI/4; it += 256)
      *(float4*)&sh[it*4] = *(const float4*)&ws[zb + it*4];
    __syncthreads();
    if (tid < 64){
      int c = tid;
      const void* whhp = d ? whhb : whhf;
      float wreg[CI];
      if (mode){
        const uint4* wq = (const uint4*)((const unsigned short*)whhp + c*CI);
        #pragma unroll
        for (int k = 0; k < CI; k += 8){
          uint4 q = wq[k >> 3];
          bf2x(q.x,wreg[k+0],wreg[k+1]); bf2x(q.y,wreg[k+2],wreg[k+3]);
          bf2x(q.z,wreg[k+4],wreg[k+5]); bf2x(q.w,wreg[k+6],wreg[k+7]);
        }
      } else {
        const float* wf = (const float*)whhp + c*CI;
        #pragma unroll
        for (int k = 0; k < CI; k += 4){
          float4 w4 = *(const float4*)&wf[k];
          wreg[k]=w4.x; wreg[k+1]=w4.y; wreg[k+2]=w4.z; wreg[k+3]=w4.w;
        }
      }
      const int step = d ? -1 : 1;
      int tt = d ? (N-1) : 0;
      float hv = 0.f;
      float z = sh[tt*CI + c];    // single wave: DS ops in-order, no barrier needed
      for (int t = 0; t < N; ++t){
        int ti = tt + step; ti = ti < 0 ? 0 : (ti > N-1 ? N-1 : ti);
        float znext = sh[ti*CI + c];
        float s[CI];
        #pragma unroll
        for (int k = 0; k < CI; ++k) s[k] = bcastf(hv, k);   // batched readlanes
#if __has_builtin(__builtin_amdgcn_sched_barrier)
        __builtin_amdgcn_sched_barrier(0);
#endif
        float a0 = z, a1 = 0.f, a2 = 0.f, a3 = 0.f;
        #pragma unroll
        for (int k = 0; k < CI; k += 4){
          a0 = fmaf(s[k+0], wreg[k+0], a0);
          a1 = fmaf(s[k+1], wreg[k+1], a1);
          a2 = fmaf(s[k+2], wreg[k+2], a2);
          a3 = fmaf(s[k+3], wreg[k+3], a3);
        }
        float x = (a0+a1)+(a2+a3);
        x = fminf(15.f, fmaxf(-15.f, x));
        float p = __expf(2.f * x);
        hv = (p - 1.f) * __builtin_amdgcn_rcpf(p + 1.f);
        sh[tt*CI + c] = hv;
        z = znext;
        tt += step;
      }
    }
    __syncthreads();
    for (int it = tid; it < N*CI/4; it += 256)
      *(float4*)&ws[ob + it*4] = *(const float4*)&sh[it*4];
  } else {
    int task0 = blk - 32;                          // 0..511
    int task = (task0 & 7) * 64 + (task0 >> 3);    // XCD-contiguous (bijective, 512=8*64)
    int b = task >> 5, i0 = (task & 31) * 4;
    int f = tid;
    float* attT = sh;                    // 512
    float* h1l  = sh + 512;              // 1024
    float* red4 = sh + 1536;             // 4*64*20 = 5120
    for (int t = tid; t < 4*N; t += 256){
      int r = t >> 7, k = t & 127;
      attT[k*4 + r] = R[O_ATT + (b*N + i0 + r)*N + k];
    }
    __syncthreads();
    // h1 = att@H : quad-ownership (kg owns 32 k's, fq owns f-quad)
    {
      int kg = tid >> 6, fq = tid & 63;
      int k0 = kg * 32, f0 = fq * 4;
      float a4[4][4] = {{0,0,0,0},{0,0,0,0},{0,0,0,0},{0,0,0,0}};
      #pragma unroll 4
      for (int k = k0; k < k0+32; ++k){
        float4 h4 = *(const float4*)&R[O_H + (b*N + k)*FOUT + f0];  // coalesced 16B/lane
        float4 at = *(const float4*)&attT[k*4];                     // wave-uniform broadcast
        a4[0][0] += at.x*h4.x; a4[0][1] += at.x*h4.y; a4[0][2] += at.x*h4.z; a4[0][3] += at.x*h4.w;
        a4[1][0] += at.y*h4.x; a4[1][1] += at.y*h4.y; a4[1][2] += at.y*h4.z; a4[1][3] += at.y*h4.w;
        a4[2][0] += at.z*h4.x; a4[2][1] += at.z*h4.y; a4[2][2] += at.z*h4.z; a4[2][3] += at.z*h4.w;
        a4[3][0] += at.w*h4.x; a4[3][1] += at.w*h4.y; a4[3][2] += at.w*h4.z; a4[3][3] += at.w*h4.w;
      }
      float* rp = &red4[(kg*64 + fq)*20];
      #pragma unroll
      for (int r = 0; r < 4; ++r)
        *(float4*)&rp[r*4] = *(const float4*)&a4[r][0];
    }
    __syncthreads();
    {
      int fq2 = f >> 2, j = f & 3;
      #pragma unroll
      for (int r = 0; r < 4; ++r){
        float s0 = red4[(0*64+fq2)*20 + r*4 + j];
        float s1 = red4[(1*64+fq2)*20 + r*4 + j];
        float s2 = red4[(2*64+fq2)*20 + r*4 + j];
        float s3 = red4[(3*64+fq2)*20 + r*4 + j];
        h1l[r*FOUT + f] = (s0+s1)+(s2+s3);
      }
    }
    __syncthreads();   // h1l ready; also fences red4 reads before re-use below
    // partial = h1 @ fco_w[2CI:,:] : l-quad ownership (64 vector loads/thread)
    {
      int cg = tid >> 6, lq = tid & 63;
      int c0 = cg * 64, l0 = lq * 4;
      float p44[4][4] = {{0,0,0,0},{0,0,0,0},{0,0,0,0},{0,0,0,0}};
      if (mode){
        const unsigned short* fu = (const unsigned short*)fcowp + (size_t)(2*CI)*L1;
        #pragma unroll 4
        for (int c = c0; c < c0+64; ++c){
          uint2 wq = *(const uint2*)&fu[c*L1 + l0];
          float w0,w1,w2,w3; bf2x(wq.x,w0,w1); bf2x(wq.y,w2,w3);
          #pragma unroll
          for (int r = 0; r < 4; ++r){
            float hv = h1l[r*FOUT + c];        // wave-uniform -> LDS broadcast
            p44[r][0] += hv*w0; p44[r][1] += hv*w1;
            p44[r][2] += hv*w2; p44[r][3] += hv*w3;
          }
        }
      } else {
        const float* ff = (const float*)fcowp + (size_t)(2*CI)*L1;
        #pragma unroll 4
        for (int c = c0; c < c0+64; ++c){
          float4 w4 = *(const float4*)&ff[c*L1 + l0];
          #pragma unroll
          for (int r = 0; r < 4; ++r){
            float hv = h1l[r*FOUT + c];
            p44[r][0] += hv*w4.x; p44[r][1] += hv*w4.y;
            p44[r][2] += hv*w4.z; p44[r][3] += hv*w4.w;
          }
        }
      }
      float* rp = &red4[(cg*64 + lq)*20];
      #pragma unroll
      for (int r = 0; r < 4; ++r)
        *(float4*)&rp[r*4] = *(const float4*)&p44[r][0];
    }
    __syncthreads();
    {
      int fq2 = f >> 2, j = f & 3;
      float bias = ldf(fcobp, f, mode);
      #pragma unroll
      for (int r = 0; r < 4; ++r){
        float s0 = red4[(0*64+fq2)*20 + r*4 + j];
        float s1 = red4[(1*64+fq2)*20 + r*4 + j];
        float s2 = red4[(2*64+fq2)*20 + r*4 + j];
        float s3 = red4[(3*64+fq2)*20 + r*4 + j];
        ws[O_H1 + (b*N + i0 + r)*L1 + f] = bias + (s0+s1)+(s2+s3);
      }
    }
  }
}

// K4 (thin): out = elu(partial + cat(lrelu(rf),lrelu(rb)) @ fco_w[0:2CI,:])
// f-quad ownership: 32 vector weight loads/thread instead of 128 scalar.
__global__ __launch_bounds__(256, 2) void k_out(const void* __restrict__ xr,
                                                const void* __restrict__ fcowp,
                                                const float* __restrict__ R, void* dout){
  int blk = blockIdx.x, tid = threadIdx.x;
  int b = blk >> 5, i0 = (blk & 31) * 4;
  __shared__ __align__(16) float inl[4*2*CI];     // 4 rows x 128
  __shared__ __align__(16) float red4[4*64*20];   // partials, stride 20
  int mode = blk_mode(xr, 256, tid);
  for (int t = tid; t < 4*2*CI; t += 256){
    int r = t >> 7, k = t & 127;
    int row = b*N + i0 + r;
    inl[r*128 + k] = (k < CI) ? lrelu(R[O_RF + row*CI + k])
                              : lrelu(R[O_RB + row*CI + (k - CI)]);
  }
  __syncthreads();
  // thread=(cg,lq): cg owns 32 c's, lq owns l-quad
  {
    int cg = tid >> 6, lq = tid & 63;
    int c0 = cg * 32, l0 = lq * 4;
    float a4[4][4] = {{0,0,0,0},{0,0,0,0},{0,0,0,0},{0,0,0,0}};
    if (mode){
      const unsigned short* fu = (const unsigned short*)fcowp;
      #pragma unroll 4
      for (int c = c0; c < c0+32; ++c){
        uint2 wq = *(const uint2*)&fu[c*L1 + l0];
        float w0,w1,w2,w3; bf2x(wq.x,w0,w1); bf2x(wq.y,w2,w3);
        #pragma unroll
        for (int r = 0; r < 4; ++r){
          float xv = inl[r*128 + c];          // wave-uniform -> LDS broadcast
          a4[r][0] += xv*w0; a4[r][1] += xv*w1;
          a4[r][2] += xv*w2; a4[r][3] += xv*w3;
        }
      }
    } else {
      const float* ff = (const float*)fcowp;
      #pragma unroll 4
      for (int c = c0; c < c0+32; ++c){
        float4 w4 = *(const float4*)&ff[c*L1 + l0];
        #pragma unroll
        for (int r = 0; r < 4; ++r){
          float xv = inl[r*128 + c];
          a4[r][0] += xv*w4.x; a4[r][1] += xv*w4.y;
          a4[r][2] += xv*w4.z; a4[r][3] += xv*w4.w;
        }
      }
    }
    float* rp = &red4[(cg*64 + lq)*20];
    #pragma unroll
    for (int r = 0; r < 4; ++r)
      *(float4*)&rp[r*4] = *(const float4*)&a4[r][0];
  }
  __syncthreads();
  int l = tid;
  {
    int fq2 = l >> 2, j = l & 3;
    #pragma unroll
    for (int r = 0; r < 4; ++r){
      float s0 = red4[(0*64+fq2)*20 + r*4 + j];
      float s1 = red4[(1*64+fq2)*20 + r*4 + j];
      float s2 = red4[(2*64+fq2)*20 + r*4 + j];
      float s3 = red4[(3*64+fq2)*20 + r*4 + j];
      float acc = R[O_H1 + (b*N + i0 + r)*L1 + l] + (s0+s1)+(s2+s3);
      float o = acc > 0.f ? acc : expm1f(acc);
      int idx = (b*N + i0 + r)*L1 + l;
      if (mode) ((__hip_bfloat16*)dout)[idx] = __float2bfloat16(o);
      else      ((float*)dout)[idx] = o;
    }
  }
}

extern "C" void kernel_launch(void* const* d_in, const int* in_sizes, int n_in,
                              void* d_out, int out_size, void* d_ws, size_t ws_size,
                              hipStream_t stream){
  (void)in_sizes; (void)n_in; (void)out_size; (void)ws_size;
  float* ws = (float*)d_ws;
  AttArgs A;
  A.we = d_in[2]; A.x = d_in[0]; A.wfcw = d_in[5]; A.wfcb = d_in[6];
  A.fcw = d_in[7]; A.fcb = d_in[8]; A.fccb = d_in[10];
  A.wihf = d_in[11]; A.bihf = d_in[13]; A.bhhf = d_in[14];
  A.wihb = d_in[15]; A.bihb = d_in[17]; A.bhhb = d_in[18];
  hipLaunchKernelGGL(k_h_pq,   dim3(512),    dim3(256), 0, stream,
                     d_in[0], d_in[3], d_in[4], d_in[9], d_in[7], ws);
  hipLaunchKernelGGL(k_att,    dim3(B*N/2),  dim3(256), 0, stream, A, (const int*)d_in[1], ws);
  hipLaunchKernelGGL(k_rnn_h1, dim3(544),    dim3(256), 0, stream,
                     d_in[0], d_in[12], d_in[16], d_in[19], d_in[20], ws);
  hipLaunchKernelGGL(k_out,    dim3(512),    dim3(256), 0, stream,
                     d_in[0], d_in[19], ws, d_out);
}